// Round 7
// baseline (119.760 us; speedup 1.0000x reference)
//
#include <hip/hip_runtime.h>
#include <stdint.h>

typedef unsigned short u16;
typedef short s16x8 __attribute__((ext_vector_type(8)));
typedef short s16x4 __attribute__((ext_vector_type(4)));
typedef float f32x4 __attribute__((ext_vector_type(4)));
typedef uint32_t u32x4 __attribute__((ext_vector_type(4)));

#define SCALE 0.17677669529663689f
#define LOG2E 1.4426950408889634f
#define QS (SCALE * LOG2E)
#define EPS 1e-5f

static __device__ __forceinline__ u16 f2b(float f){   // RNE
  uint32_t u = __float_as_uint(f);
  uint32_t r = (u + 0x7FFFu + ((u >> 16) & 1u)) >> 16;
  return (u16)r;
}
static __device__ __forceinline__ uint32_t cvtpk(float lo, float hi){
  uint32_t r;
  asm("v_cvt_pk_bf16_f32 %0, %1, %2" : "=v"(r) : "v"(lo), "v"(hi));
  return r;
}

// ---- K0: repack srw/pw into B-frag order (weights only) ----
__global__ __launch_bounds__(256) void k_prep(const float* __restrict__ srw,
                                              const float* __restrict__ pw,
                                              u16* __restrict__ wsr,
                                              u16* __restrict__ wpj){
  const int t = blockIdx.x*256 + threadIdx.x;
  if (t < 262144){
    const int co = t >> 10, k = t & 1023;
    const float v = srw[(co<<10) + ((k&255)<<2) + (k>>8)];
    wsr[((((k>>3)<<8) + co)<<3) + (k&7)] = f2b(v);
  } else if (t < 327680){
    const int u2 = t - 262144;
    const int co = u2 >> 8, k = u2 & 255;
    wpj[((((k>>3)<<8) + co)<<3) + (k&7)] = f2b(pw[(co<<8) + k]);
  }
}

// ---- K1: depthwise 3x3 Q conv (fp32 x in), 8-px strips; emits bf16 x copy; Q pre-scaled ----
__global__ __launch_bounds__(256) void k_qconv(const float* __restrict__ x,
                                               const float* __restrict__ w,
                                               u16* __restrict__ q,
                                               u16* __restrict__ xbf){
  const int c = threadIdx.x;
  const int blk = blockIdx.x;            // b*512 + y*8 + xs
  const int b = blk >> 9;
  const int y = (blk >> 3) & 63;
  const int x0 = (blk & 7) << 3;
  float wv[9];
#pragma unroll
  for (int t = 0; t < 9; ++t) wv[t] = w[c*9 + t];
  float xin[3][10];
#pragma unroll
  for (int r = 0; r < 3; ++r){
    const int yy = y + r - 1;
    const bool yok = (unsigned)yy < 64u;
#pragma unroll
    for (int j = 0; j < 10; ++j){
      const int xx = x0 + j - 1;
      const bool ok = yok && ((unsigned)xx < 64u);
      xin[r][j] = ok ? x[(((b<<12) + (yy<<6) + xx) << 8) + c] : 0.f;
    }
  }
#pragma unroll
  for (int j = 0; j < 8; ++j){
    float acc = 0.f;
#pragma unroll
    for (int r = 0; r < 3; ++r)
#pragma unroll
      for (int t = 0; t < 3; ++t)
        acc += xin[r][j+t] * wv[r*3 + t];
    const int idx = (((b<<12) + (y<<6) + x0 + j) << 8) + c;
    q[idx]   = f2b(acc * QS);
    xbf[idx] = f2b(xin[1][j+1]);
  }
}

// ---- K2: SR conv as MFMA GEMM, M-tile 64/block (wave = 16 rows x all 256 co) + LN ----
__global__ __launch_bounds__(256) void k_srgemm(const u16* __restrict__ xbf,
                                                const u16* __restrict__ wsr,
                                                const float* __restrict__ srb,
                                                const float* __restrict__ lng,
                                                const float* __restrict__ lnb,
                                                float* __restrict__ lnxr){
  const int tid = threadIdx.x;
  const int l = tid & 63, w = tid >> 6;
  const int r15 = l & 15, g = l >> 4;
  const int m0 = (blockIdx.x << 6) + (w << 4);   // wave's 16 im2col rows
  const int ma = m0 + r15;
  const int bb_ = ma >> 10, nk = ma & 1023;
  const int hs = nk >> 5, wsx = nk & 31;
  int pixbase[4];
#pragma unroll
  for (int p = 0; p < 4; ++p){
    const int y = 2*hs + (p>>1), xx = 2*wsx + (p&1);
    pixbase[p] = (((bb_<<12) + (y<<6) + xx) << 8);
  }
  f32x4 acc[16];
#pragma unroll
  for (int i = 0; i < 16; ++i) acc[i] = (f32x4){0.f,0.f,0.f,0.f};
  for (int ks = 0; ks < 32; ++ks){
    const s16x8 af = *reinterpret_cast<const s16x8*>(
        xbf + pixbase[ks>>3] + ((ks&7)<<5) + (g<<3));
#pragma unroll
    for (int i = 0; i < 16; ++i){
      const s16x8 bf = *reinterpret_cast<const s16x8*>(
          wsr + (((((ks<<2)+g)<<8) + (i<<4)+r15)<<3));
      acc[i] = __builtin_amdgcn_mfma_f32_16x16x32_bf16(af, bf, acc[i], 0, 0, 0);
    }
  }
#pragma unroll
  for (int i = 0; i < 16; ++i){
    const float sb = srb[(i<<4)+r15];
#pragma unroll
    for (int r = 0; r < 4; ++r) acc[i][r] += sb;
  }
  float mu_r[4], rs_r[4];
#pragma unroll
  for (int r = 0; r < 4; ++r){
    float s = 0.f, qq = 0.f;
#pragma unroll
    for (int i = 0; i < 16; ++i){ const float v = acc[i][r]; s += v; qq += v*v; }
#pragma unroll
    for (int off = 1; off < 16; off <<= 1){
      s  += __shfl_xor(s, off);
      qq += __shfl_xor(qq, off);
    }
    const float mu = s * (1.f/256.f);
    mu_r[r] = mu;
    rs_r[r] = rsqrtf(qq*(1.f/256.f) - mu*mu + EPS);
  }
#pragma unroll
  for (int i = 0; i < 16; ++i){
    const int co = (i<<4)+r15;
    const float gv = lng[co], bv = lnb[co];
#pragma unroll
    for (int r = 0; r < 4; ++r)
      lnxr[(m0+(g<<2)+r)*256 + co] = (acc[i][r]-mu_r[r])*rs_r[r]*gv + bv;
  }
}

// ---- K3: depthwise 3x3 KV conv, 8-px strips; K [bh,nk,32], V [bh,32,Nk] (block-swizzled) ----
__global__ __launch_bounds__(512) void k_kvconv(const float* __restrict__ lnxr,
                                                const float* __restrict__ w,
                                                u16* __restrict__ kbuf,
                                                u16* __restrict__ vT){
  const int o = threadIdx.x;             // 0..511
  const int blk = blockIdx.x;            // b*128 + y*4 + xs
  const int b = blk >> 7;
  const int y = (blk >> 2) & 31;
  const int x0 = (blk & 3) << 3;
  const int g = o >> 1;
  float wv[9];
#pragma unroll
  for (int t = 0; t < 9; ++t) wv[t] = w[o*9 + t];
  float xin[3][10];
#pragma unroll
  for (int r = 0; r < 3; ++r){
    const int yy = y + r - 1;
    const bool yok = (unsigned)yy < 32u;
#pragma unroll
    for (int j = 0; j < 10; ++j){
      const int xx = x0 + j - 1;
      const bool ok = yok && ((unsigned)xx < 32u);
      xin[r][j] = ok ? lnxr[(((b<<10) + (yy<<5) + xx) << 8) + g] : 0.f;
    }
  }
  float acc[8];
#pragma unroll
  for (int j = 0; j < 8; ++j){
    float a = 0.f;
#pragma unroll
    for (int r = 0; r < 3; ++r)
#pragma unroll
      for (int t = 0; t < 3; ++t)
        a += xin[r][j+t] * wv[r*3 + t];
    acc[j] = a;
  }
  const int t = o & 255;
  const int h = t >> 5, dd = t & 31;
  if (o < 256){
    const int nkbase = (((b<<3) + h) << 10) + (y<<5) + x0;
#pragma unroll
    for (int j = 0; j < 8; ++j)
      kbuf[((nkbase + j) << 5) + dd] = f2b(acc[j]);
  } else {
    s16x8 pack;
#pragma unroll
    for (int j = 0; j < 8; ++j) pack[j] = (short)f2b(acc[j]);
    const int col0 = (y<<5) + x0;
    const int colS = (((col0>>3) ^ (dd&7)) << 3);   // 16B-block XOR swizzle
    *reinterpret_cast<s16x8*>(
        vT + (((((b<<3) + h) << 5) + dd) << 10) + colS) = pack;
  }
}

// ---- K4: MFMA flash attention; whole-head K/V resident in LDS ----
// 256 blocks x 512 thr; block = (b,h, 512-query chunk); 8 waves x 64 queries
__global__ __launch_bounds__(512) void k_attn(const u16* __restrict__ q,
                                              const u16* __restrict__ kbuf,
                                              const u16* __restrict__ vT,
                                              u16* __restrict__ attb){
  __shared__ __align__(16) u16 KL[32768];   // [nk][32]
  __shared__ __align__(16) u16 VL[32768];   // [d][1024], 16B blocks swizzled by d&7
  const int tid = threadIdx.x;
  const int l = tid & 63, w = tid >> 6;
  const int i = blockIdx.x;
  const int xcd = i & 7, slot = i >> 3;
  const int bh = (xcd<<2) + (slot>>3);
  const int chunk = slot & 7;
  const int b = bh >> 3, h = bh & 7;
  const int r15 = l & 15, g = l >> 4;
  const int n0 = (chunk<<9) + (w<<6);

  {
    const uint4* kg = (const uint4*)(kbuf + (bh<<15));
    const uint4* vg = (const uint4*)(vT   + (bh<<15));
    uint4* kl = (uint4*)KL;
    uint4* vl = (uint4*)VL;
#pragma unroll
    for (int r = 0; r < 8; ++r){
      kl[(r<<9) + tid] = kg[(r<<9) + tid];
      vl[(r<<9) + tid] = vg[(r<<9) + tid];
    }
  }
  __syncthreads();

  s16x8 qf[4];
#pragma unroll
  for (int qi = 0; qi < 4; ++qi)
    qf[qi] = *reinterpret_cast<const s16x8*>(
        q + (((b<<12) + n0 + (qi<<4) + r15) << 8) + (h<<5) + (g<<3));

  f32x4 acc[4][2];
#pragma unroll
  for (int qi = 0; qi < 4; ++qi){
    acc[qi][0] = (f32x4){0.f,0.f,0.f,0.f};
    acc[qi][1] = (f32x4){0.f,0.f,0.f,0.f};
  }
  const f32x4 zero = {0.f,0.f,0.f,0.f};
  float lsum[4] = {0.f,0.f,0.f,0.f};
  const int vswz = (r15 & 7);

  for (int kv0 = 0; kv0 < 1024; kv0 += 64){
    s16x8 kf[4];
#pragma unroll
    for (int st = 0; st < 4; ++st)
      kf[st] = *reinterpret_cast<const s16x8*>(
          KL + ((kv0 + (st<<4) + r15) << 5) + (g<<3));
    s16x8 vf[2][2];
#pragma unroll
    for (int pr = 0; pr < 2; ++pr)
#pragma unroll
      for (int h2 = 0; h2 < 2; ++h2){
        const int cl  = kv0 + (pr<<5) + (g<<2);
        const int cl2 = cl + 16;
        const int rb  = ((h2<<4) + r15) << 10;
        const s16x4 v0 = *reinterpret_cast<const s16x4*>(
            VL + rb + (((cl >>3) ^ vswz) << 3) + (cl &7));
        const s16x4 v1 = *reinterpret_cast<const s16x4*>(
            VL + rb + (((cl2>>3) ^ vswz) << 3) + (cl2&7));
        s16x8 vv;
        vv[0]=v0[0]; vv[1]=v0[1]; vv[2]=v0[2]; vv[3]=v0[3];
        vv[4]=v1[0]; vv[5]=v1[1]; vv[6]=v1[2]; vv[7]=v1[3];
        vf[pr][h2] = vv;
      }
#pragma unroll
    for (int qi = 0; qi < 4; ++qi){
      f32x4 s[4];
      __builtin_amdgcn_s_setprio(1);
#pragma unroll
      for (int st = 0; st < 4; ++st)
        s[st] = __builtin_amdgcn_mfma_f32_16x16x32_bf16(kf[st], qf[qi], zero, 0, 0, 0);
      __builtin_amdgcn_s_setprio(0);
      float p[4][4];
      float ps = 0.f;
#pragma unroll
      for (int st = 0; st < 4; ++st)
#pragma unroll
        for (int r = 0; r < 4; ++r){
          const float e = __builtin_amdgcn_exp2f(s[st][r]);
          p[st][r] = e;
          ps += e;
        }
      ps += __shfl_xor(ps, 16);
      ps += __shfl_xor(ps, 32);
      lsum[qi] += ps;
      const u32x4 pk0 = {cvtpk(p[0][0],p[0][1]), cvtpk(p[0][2],p[0][3]),
                         cvtpk(p[1][0],p[1][1]), cvtpk(p[1][2],p[1][3])};
      const u32x4 pk1 = {cvtpk(p[2][0],p[2][1]), cvtpk(p[2][2],p[2][3]),
                         cvtpk(p[3][0],p[3][1]), cvtpk(p[3][2],p[3][3])};
      const s16x8 pf0 = __builtin_bit_cast(s16x8, pk0);
      const s16x8 pf1 = __builtin_bit_cast(s16x8, pk1);
      __builtin_amdgcn_s_setprio(1);
#pragma unroll
      for (int h2 = 0; h2 < 2; ++h2){
        acc[qi][h2] = __builtin_amdgcn_mfma_f32_16x16x32_bf16(pf0, vf[0][h2], acc[qi][h2], 0, 0, 0);
        acc[qi][h2] = __builtin_amdgcn_mfma_f32_16x16x32_bf16(pf1, vf[1][h2], acc[qi][h2], 0, 0, 0);
      }
      __builtin_amdgcn_s_setprio(0);
    }
  }
#pragma unroll
  for (int qi = 0; qi < 4; ++qi){
    const float linv = 1.f / lsum[qi];
#pragma unroll
    for (int r = 0; r < 4; ++r){
      const float fl = __shfl(linv, (g<<2) + r);
      const int n = n0 + (qi<<4) + (g<<2) + r;
      u16* orow = attb + (((b<<12) + n) << 8) + (h<<5) + r15;
      orow[0]  = f2b(acc[qi][0][r] * fl);
      orow[16] = f2b(acc[qi][1][r] * fl);
    }
  }
}

// ---- K5: projection as MFMA GEMM, M-tile 64/block (wave = 16 rows x all co) ----
__global__ __launch_bounds__(256) void k_proj(const u16* __restrict__ attb,
                                              const u16* __restrict__ wpj,
                                              const float* __restrict__ pb,
                                              float* __restrict__ out){
  const int tid = threadIdx.x;
  const int l = tid & 63, w = tid >> 6;
  const int r15 = l & 15, g = l >> 4;
  const int m0 = (blockIdx.x << 6) + (w << 4);
  f32x4 acc[16];
#pragma unroll
  for (int i = 0; i < 16; ++i) acc[i] = (f32x4){0.f,0.f,0.f,0.f};
  const u16* arow = attb + (m0 + r15)*256 + (g<<3);
#pragma unroll
  for (int ks = 0; ks < 8; ++ks){
    const s16x8 af = *reinterpret_cast<const s16x8*>(arow + (ks<<5));
#pragma unroll
    for (int i = 0; i < 16; ++i){
      const s16x8 bf = *reinterpret_cast<const s16x8*>(
          wpj + (((((ks<<2)+g)<<8) + (i<<4)+r15)<<3));
      acc[i] = __builtin_amdgcn_mfma_f32_16x16x32_bf16(af, bf, acc[i], 0, 0, 0);
    }
  }
#pragma unroll
  for (int i = 0; i < 16; ++i){
    const int co = (i<<4)+r15;
    const float pbv = pb[co];
#pragma unroll
    for (int r = 0; r < 4; ++r)
      out[(m0+(g<<2)+r)*256 + co] = acc[i][r] + pbv;
  }
}

extern "C" void kernel_launch(void* const* d_in, const int* in_sizes, int n_in,
                              void* d_out, int out_size, void* d_ws, size_t ws_size,
                              hipStream_t stream){
  const float* x   = (const float*)d_in[0];
  const float* qw  = (const float*)d_in[1];
  const float* kvw = (const float*)d_in[2];
  const float* srw = (const float*)d_in[3];
  const float* srb = (const float*)d_in[4];
  const float* lng = (const float*)d_in[5];
  const float* lnb = (const float*)d_in[6];
  const float* pw  = (const float*)d_in[7];
  const float* pb  = (const float*)d_in[8];
  float* out = (float*)d_out;

  char* ws = (char*)d_ws;
  u16*   qbuf = (u16*)(ws);                   // 8 MiB  [B,N,C] bf16 (pre-scaled)
  u16*   xbf  = (u16*)(ws + 8388608);         // 8 MiB  [B,N,C] bf16 copy of x
  u16*   attb = (u16*)(ws + 8388608);         // aliases xbf (dead after srgemm)
  float* lnxr = (float*)(ws + 16777216);      // 4 MiB  [B,Nk,C] f32
  u16*   kbuf = (u16*)(ws + 20971520);        // 2 MiB  [bh,Nk,d] bf16
  u16*   vT   = (u16*)(ws + 23068672);        // 2 MiB  [bh,d,Nk] bf16 (swizzled)
  u16*   wsr  = (u16*)(ws + 25165824);        // 512 KiB repacked SR weights
  u16*   wpj  = (u16*)(ws + 25690112);        // 128 KiB repacked proj weights

  hipLaunchKernelGGL(k_prep,   dim3(1280), dim3(256), 0, stream, srw, pw, wsr, wpj);
  hipLaunchKernelGGL(k_qconv,  dim3(2048), dim3(256), 0, stream, x, qw, qbuf, xbf);
  hipLaunchKernelGGL(k_srgemm, dim3(64),   dim3(256), 0, stream, xbf, wsr, srb, lng, lnb, lnxr);
  hipLaunchKernelGGL(k_kvconv, dim3(512),  dim3(512), 0, stream, lnxr, kvw, kbuf, vT);
  hipLaunchKernelGGL(k_attn,   dim3(256),  dim3(512), 0, stream, qbuf, kbuf, vT, attb);
  hipLaunchKernelGGL(k_proj,   dim3(256),  dim3(256), 0, stream, attb, wpj, pb, out);
}

// Round 8
// 78.996 us; speedup vs baseline: 1.5160x; 1.5160x over previous
//
#include <hip/hip_runtime.h>
#include <stdint.h>

typedef unsigned short u16;
typedef short s16x8 __attribute__((ext_vector_type(8)));
typedef short s16x4 __attribute__((ext_vector_type(4)));
typedef float f32x4 __attribute__((ext_vector_type(4)));
typedef uint32_t u32x4 __attribute__((ext_vector_type(4)));

#define SCALE 0.17677669529663689f
#define LOG2E 1.4426950408889634f
#define QS (SCALE * LOG2E)
#define EPS 1e-5f

static __device__ __forceinline__ u16 f2b(float f){   // RNE
  uint32_t u = __float_as_uint(f);
  uint32_t r = (u + 0x7FFFu + ((u >> 16) & 1u)) >> 16;
  return (u16)r;
}
static __device__ __forceinline__ uint32_t cvtpk(float lo, float hi){
  uint32_t r;
  asm("v_cvt_pk_bf16_f32 %0, %1, %2" : "=v"(r) : "v"(lo), "v"(hi));
  return r;
}

// ---- K1: depthwise 3x3 Q conv (fp32 x), 8-px strips; emits bf16 x copy; Q pre-scaled.
//      Extra blocks (>=2048) repack srw/pw into B-frag order. ----
__global__ __launch_bounds__(256) void k_qconv(const float* __restrict__ x,
                                               const float* __restrict__ w,
                                               const float* __restrict__ srw,
                                               const float* __restrict__ pw,
                                               u16* __restrict__ q,
                                               u16* __restrict__ xbf,
                                               u16* __restrict__ wsr,
                                               u16* __restrict__ wpj){
  const int blk = blockIdx.x;
  if (blk >= 2048){
    const int t = (blk - 2048)*256 + threadIdx.x;
    if (t < 262144){
      const int co = t >> 10, k = t & 1023;
      const float v = srw[(co<<10) + ((k&255)<<2) + (k>>8)];
      wsr[((((k>>3)<<8) + co)<<3) + (k&7)] = f2b(v);
    } else if (t < 327680){
      const int u2 = t - 262144;
      const int co = u2 >> 8, k = u2 & 255;
      wpj[((((k>>3)<<8) + co)<<3) + (k&7)] = f2b(pw[(co<<8) + k]);
    }
    return;
  }
  const int c = threadIdx.x;
  const int b = blk >> 9;
  const int y = (blk >> 3) & 63;
  const int x0 = (blk & 7) << 3;
  float wv[9];
#pragma unroll
  for (int t = 0; t < 9; ++t) wv[t] = w[c*9 + t];
  float xin[3][10];
#pragma unroll
  for (int r = 0; r < 3; ++r){
    const int yy = y + r - 1;
    const bool yok = (unsigned)yy < 64u;
#pragma unroll
    for (int j = 0; j < 10; ++j){
      const int xx = x0 + j - 1;
      const bool ok = yok && ((unsigned)xx < 64u);
      xin[r][j] = ok ? x[(((b<<12) + (yy<<6) + xx) << 8) + c] : 0.f;
    }
  }
#pragma unroll
  for (int j = 0; j < 8; ++j){
    float acc = 0.f;
#pragma unroll
    for (int r = 0; r < 3; ++r)
#pragma unroll
      for (int t = 0; t < 3; ++t)
        acc += xin[r][j+t] * wv[r*3 + t];
    const int idx = (((b<<12) + (y<<6) + x0 + j) << 8) + c;
    q[idx]   = f2b(acc * QS);
    xbf[idx] = f2b(xin[1][j+1]);
  }
}

// ---- K2: SR conv as MFMA GEMM (M=4096,N=256,K=1024) + bias + fused LayerNorm ----
// round-6 shape: 256 blocks x 256 thr; wave = 16 rows x 4 co-tiles; LDS LN reduce
__global__ __launch_bounds__(256) void k_srgemm(const u16* __restrict__ xbf,
                                                const u16* __restrict__ wsr,
                                                const float* __restrict__ srb,
                                                const float* __restrict__ lng,
                                                const float* __restrict__ lnb,
                                                float* __restrict__ lnxr){
  __shared__ float red_s[16][4], red_q[16][4];
  __shared__ float mu_s[16], rs_s[16];
  const int tid = threadIdx.x;
  const int l = tid & 63, w = tid >> 6;
  const int r15 = l & 15, g = l >> 4;
  const int m0 = blockIdx.x << 4;
  const int ma = m0 + r15;
  const int bb_ = ma >> 10, nk = ma & 1023;
  const int hs = nk >> 5, wsx = nk & 31;
  int pixbase[4];
#pragma unroll
  for (int p = 0; p < 4; ++p){
    const int y = 2*hs + (p>>1), xx = 2*wsx + (p&1);
    pixbase[p] = (((bb_<<12) + (y<<6) + xx) << 8);
  }
  f32x4 acc[4];
#pragma unroll
  for (int i = 0; i < 4; ++i) acc[i] = (f32x4){0.f,0.f,0.f,0.f};
  for (int ks = 0; ks < 32; ++ks){
    const s16x8 af = *reinterpret_cast<const s16x8*>(
        xbf + pixbase[ks>>3] + ((ks&7)<<5) + (g<<3));
#pragma unroll
    for (int i = 0; i < 4; ++i){
      const int co = (((w<<2)+i)<<4) + r15;
      const s16x8 bf = *reinterpret_cast<const s16x8*>(
          wsr + (((((ks<<2)+g)<<8) + co)<<3));
      acc[i] = __builtin_amdgcn_mfma_f32_16x16x32_bf16(af, bf, acc[i], 0, 0, 0);
    }
  }
  float gv[4], bv[4];
#pragma unroll
  for (int i = 0; i < 4; ++i){
    const int co = (((w<<2)+i)<<4) + r15;
    const float sb = srb[co];
    gv[i] = lng[co]; bv[i] = lnb[co];
#pragma unroll
    for (int r = 0; r < 4; ++r) acc[i][r] += sb;
  }
  float s_r[4], q_r[4];
#pragma unroll
  for (int r = 0; r < 4; ++r){
    float s = 0.f, qq = 0.f;
#pragma unroll
    for (int i = 0; i < 4; ++i){ const float v = acc[i][r]; s += v; qq += v*v; }
#pragma unroll
    for (int off = 1; off < 16; off <<= 1){
      s  += __shfl_xor(s, off);
      qq += __shfl_xor(qq, off);
    }
    s_r[r] = s; q_r[r] = qq;
  }
  if (r15 == 0){
#pragma unroll
    for (int r = 0; r < 4; ++r){
      red_s[(g<<2)+r][w] = s_r[r];
      red_q[(g<<2)+r][w] = q_r[r];
    }
  }
  __syncthreads();
  if (tid < 16){
    const float s  = red_s[tid][0]+red_s[tid][1]+red_s[tid][2]+red_s[tid][3];
    const float qq = red_q[tid][0]+red_q[tid][1]+red_q[tid][2]+red_q[tid][3];
    const float mu = s * (1.f/256.f);
    mu_s[tid] = mu;
    rs_s[tid] = rsqrtf(qq*(1.f/256.f) - mu*mu + EPS);
  }
  __syncthreads();
  float mur[4], rsr[4];
#pragma unroll
  for (int r = 0; r < 4; ++r){ mur[r] = mu_s[(g<<2)+r]; rsr[r] = rs_s[(g<<2)+r]; }
#pragma unroll
  for (int i = 0; i < 4; ++i){
    const int co = (((w<<2)+i)<<4) + r15;
#pragma unroll
    for (int r = 0; r < 4; ++r)
      lnxr[(m0+(g<<2)+r)*256 + co] = (acc[i][r]-mur[r])*rsr[r]*gv[i] + bv[i];
  }
}

// ---- K3: depthwise 3x3 KV conv, 8-px strips; K [bh,nk,32], V [bh,32,Nk] (block-swizzled) ----
__global__ __launch_bounds__(512) void k_kvconv(const float* __restrict__ lnxr,
                                                const float* __restrict__ w,
                                                u16* __restrict__ kbuf,
                                                u16* __restrict__ vT){
  const int o = threadIdx.x;             // 0..511
  const int blk = blockIdx.x;            // b*128 + y*4 + xs
  const int b = blk >> 7;
  const int y = (blk >> 2) & 31;
  const int x0 = (blk & 3) << 3;
  const int g = o >> 1;
  float wv[9];
#pragma unroll
  for (int t = 0; t < 9; ++t) wv[t] = w[o*9 + t];
  float xin[3][10];
#pragma unroll
  for (int r = 0; r < 3; ++r){
    const int yy = y + r - 1;
    const bool yok = (unsigned)yy < 32u;
#pragma unroll
    for (int j = 0; j < 10; ++j){
      const int xx = x0 + j - 1;
      const bool ok = yok && ((unsigned)xx < 32u);
      xin[r][j] = ok ? lnxr[(((b<<10) + (yy<<5) + xx) << 8) + g] : 0.f;
    }
  }
  float acc[8];
#pragma unroll
  for (int j = 0; j < 8; ++j){
    float a = 0.f;
#pragma unroll
    for (int r = 0; r < 3; ++r)
#pragma unroll
      for (int t = 0; t < 3; ++t)
        a += xin[r][j+t] * wv[r*3 + t];
    acc[j] = a;
  }
  const int t = o & 255;
  const int h = t >> 5, dd = t & 31;
  if (o < 256){
    const int nkbase = (((b<<3) + h) << 10) + (y<<5) + x0;
#pragma unroll
    for (int j = 0; j < 8; ++j)
      kbuf[((nkbase + j) << 5) + dd] = f2b(acc[j]);
  } else {
    s16x8 pack;
#pragma unroll
    for (int j = 0; j < 8; ++j) pack[j] = (short)f2b(acc[j]);
    const int col0 = (y<<5) + x0;
    const int colS = (((col0>>3) ^ (dd&7)) << 3);   // 16B-block XOR swizzle
    *reinterpret_cast<s16x8*>(
        vT + (((((b<<3) + h) << 5) + dd) << 10) + colS) = pack;
  }
}

// ---- K4: MFMA flash attention; whole-head K/V resident in LDS ----
// 256 blocks x 512 thr; block = (b,h, 512-query chunk); 8 waves x 64 queries
__global__ __launch_bounds__(512) void k_attn(const u16* __restrict__ q,
                                              const u16* __restrict__ kbuf,
                                              const u16* __restrict__ vT,
                                              u16* __restrict__ attb){
  __shared__ __align__(16) u16 KL[32768];   // [nk][32]
  __shared__ __align__(16) u16 VL[32768];   // [d][1024], 16B blocks swizzled by d&7
  const int tid = threadIdx.x;
  const int l = tid & 63, w = tid >> 6;
  const int i = blockIdx.x;
  const int xcd = i & 7, slot = i >> 3;
  const int bh = (xcd<<2) + (slot>>3);
  const int chunk = slot & 7;
  const int b = bh >> 3, h = bh & 7;
  const int r15 = l & 15, g = l >> 4;
  const int n0 = (chunk<<9) + (w<<6);

  {
    const uint4* kg = (const uint4*)(kbuf + (bh<<15));
    const uint4* vg = (const uint4*)(vT   + (bh<<15));
    uint4* kl = (uint4*)KL;
    uint4* vl = (uint4*)VL;
#pragma unroll
    for (int r = 0; r < 8; ++r){
      kl[(r<<9) + tid] = kg[(r<<9) + tid];
      vl[(r<<9) + tid] = vg[(r<<9) + tid];
    }
  }
  __syncthreads();

  s16x8 qf[4];
#pragma unroll
  for (int qi = 0; qi < 4; ++qi)
    qf[qi] = *reinterpret_cast<const s16x8*>(
        q + (((b<<12) + n0 + (qi<<4) + r15) << 8) + (h<<5) + (g<<3));

  f32x4 acc[4][2];
#pragma unroll
  for (int qi = 0; qi < 4; ++qi){
    acc[qi][0] = (f32x4){0.f,0.f,0.f,0.f};
    acc[qi][1] = (f32x4){0.f,0.f,0.f,0.f};
  }
  const f32x4 zero = {0.f,0.f,0.f,0.f};
  float lsum[4] = {0.f,0.f,0.f,0.f};
  const int vswz = (r15 & 7);

  for (int kv0 = 0; kv0 < 1024; kv0 += 64){
    s16x8 kf[4];
#pragma unroll
    for (int st = 0; st < 4; ++st)
      kf[st] = *reinterpret_cast<const s16x8*>(
          KL + ((kv0 + (st<<4) + r15) << 5) + (g<<3));
    s16x8 vf[2][2];
#pragma unroll
    for (int pr = 0; pr < 2; ++pr)
#pragma unroll
      for (int h2 = 0; h2 < 2; ++h2){
        const int cl  = kv0 + (pr<<5) + (g<<2);
        const int cl2 = cl + 16;
        const int rb  = ((h2<<4) + r15) << 10;
        const s16x4 v0 = *reinterpret_cast<const s16x4*>(
            VL + rb + (((cl >>3) ^ vswz) << 3) + (cl &7));
        const s16x4 v1 = *reinterpret_cast<const s16x4*>(
            VL + rb + (((cl2>>3) ^ vswz) << 3) + (cl2&7));
        s16x8 vv;
        vv[0]=v0[0]; vv[1]=v0[1]; vv[2]=v0[2]; vv[3]=v0[3];
        vv[4]=v1[0]; vv[5]=v1[1]; vv[6]=v1[2]; vv[7]=v1[3];
        vf[pr][h2] = vv;
      }
#pragma unroll
    for (int qi = 0; qi < 4; ++qi){
      f32x4 s[4];
      __builtin_amdgcn_s_setprio(1);
#pragma unroll
      for (int st = 0; st < 4; ++st)
        s[st] = __builtin_amdgcn_mfma_f32_16x16x32_bf16(kf[st], qf[qi], zero, 0, 0, 0);
      __builtin_amdgcn_s_setprio(0);
      float p[4][4];
      float ps = 0.f;
#pragma unroll
      for (int st = 0; st < 4; ++st)
#pragma unroll
        for (int r = 0; r < 4; ++r){
          const float e = __builtin_amdgcn_exp2f(s[st][r]);
          p[st][r] = e;
          ps += e;
        }
      ps += __shfl_xor(ps, 16);
      ps += __shfl_xor(ps, 32);
      lsum[qi] += ps;
      const u32x4 pk0 = {cvtpk(p[0][0],p[0][1]), cvtpk(p[0][2],p[0][3]),
                         cvtpk(p[1][0],p[1][1]), cvtpk(p[1][2],p[1][3])};
      const u32x4 pk1 = {cvtpk(p[2][0],p[2][1]), cvtpk(p[2][2],p[2][3]),
                         cvtpk(p[3][0],p[3][1]), cvtpk(p[3][2],p[3][3])};
      const s16x8 pf0 = __builtin_bit_cast(s16x8, pk0);
      const s16x8 pf1 = __builtin_bit_cast(s16x8, pk1);
      __builtin_amdgcn_s_setprio(1);
#pragma unroll
      for (int h2 = 0; h2 < 2; ++h2){
        acc[qi][h2] = __builtin_amdgcn_mfma_f32_16x16x32_bf16(pf0, vf[0][h2], acc[qi][h2], 0, 0, 0);
        acc[qi][h2] = __builtin_amdgcn_mfma_f32_16x16x32_bf16(pf1, vf[1][h2], acc[qi][h2], 0, 0, 0);
      }
      __builtin_amdgcn_s_setprio(0);
    }
  }
#pragma unroll
  for (int qi = 0; qi < 4; ++qi){
    const float linv = 1.f / lsum[qi];
#pragma unroll
    for (int r = 0; r < 4; ++r){
      const float fl = __shfl(linv, (g<<2) + r);
      const int n = n0 + (qi<<4) + (g<<2) + r;
      u16* orow = attb + (((b<<12) + n) << 8) + (h<<5) + r15;
      orow[0]  = f2b(acc[qi][0][r] * fl);
      orow[16] = f2b(acc[qi][1][r] * fl);
    }
  }
}

// ---- K5: projection as MFMA GEMM (M=16384,N=256,K=256) + bias ----
// round-6 shape: 1024 blocks x 256 thr; wave = 16 rows x 4 co-tiles
__global__ __launch_bounds__(256) void k_proj(const u16* __restrict__ attb,
                                              const u16* __restrict__ wpj,
                                              const float* __restrict__ pb,
                                              float* __restrict__ out){
  const int tid = threadIdx.x;
  const int l = tid & 63, w = tid >> 6;
  const int r15 = l & 15, g = l >> 4;
  const int m0 = blockIdx.x << 4;
  f32x4 acc[4];
#pragma unroll
  for (int i = 0; i < 4; ++i) acc[i] = (f32x4){0.f,0.f,0.f,0.f};
  const u16* arow = attb + (m0 + r15)*256 + (g<<3);
#pragma unroll
  for (int ks = 0; ks < 8; ++ks){
    const s16x8 af = *reinterpret_cast<const s16x8*>(arow + (ks<<5));
#pragma unroll
    for (int i = 0; i < 4; ++i){
      const int co = (((w<<2)+i)<<4) + r15;
      const s16x8 bf = *reinterpret_cast<const s16x8*>(
          wpj + (((((ks<<2)+g)<<8) + co)<<3));
      acc[i] = __builtin_amdgcn_mfma_f32_16x16x32_bf16(af, bf, acc[i], 0, 0, 0);
    }
  }
#pragma unroll
  for (int i = 0; i < 4; ++i){
    const int co = (((w<<2)+i)<<4) + r15;
    const float pbv = pb[co];
#pragma unroll
    for (int r = 0; r < 4; ++r)
      out[(m0+(g<<2)+r)*256 + co] = acc[i][r] + pbv;
  }
}

extern "C" void kernel_launch(void* const* d_in, const int* in_sizes, int n_in,
                              void* d_out, int out_size, void* d_ws, size_t ws_size,
                              hipStream_t stream){
  const float* x   = (const float*)d_in[0];
  const float* qw  = (const float*)d_in[1];
  const float* kvw = (const float*)d_in[2];
  const float* srw = (const float*)d_in[3];
  const float* srb = (const float*)d_in[4];
  const float* lng = (const float*)d_in[5];
  const float* lnb = (const float*)d_in[6];
  const float* pw  = (const float*)d_in[7];
  const float* pb  = (const float*)d_in[8];
  float* out = (float*)d_out;

  char* ws = (char*)d_ws;
  u16*   qbuf = (u16*)(ws);                   // 8 MiB  [B,N,C] bf16 (pre-scaled)
  u16*   xbf  = (u16*)(ws + 8388608);         // 8 MiB  [B,N,C] bf16 copy of x
  u16*   attb = (u16*)(ws + 8388608);         // aliases xbf (dead after srgemm)
  float* lnxr = (float*)(ws + 16777216);      // 4 MiB  [B,Nk,C] f32
  u16*   kbuf = (u16*)(ws + 20971520);        // 2 MiB  [bh,Nk,d] bf16
  u16*   vT   = (u16*)(ws + 23068672);        // 2 MiB  [bh,d,Nk] bf16 (swizzled)
  u16*   wsr  = (u16*)(ws + 25165824);        // 512 KiB repacked SR weights
  u16*   wpj  = (u16*)(ws + 25690112);        // 128 KiB repacked proj weights

  hipLaunchKernelGGL(k_qconv,  dim3(3328), dim3(256), 0, stream, x, qw, srw, pw, qbuf, xbf, wsr, wpj);
  hipLaunchKernelGGL(k_srgemm, dim3(256),  dim3(256), 0, stream, xbf, wsr, srb, lng, lnb, lnxr);
  hipLaunchKernelGGL(k_kvconv, dim3(512),  dim3(512), 0, stream, lnxr, kvw, kbuf, vT);
  hipLaunchKernelGGL(k_attn,   dim3(256),  dim3(512), 0, stream, qbuf, kbuf, vT, attb);
  hipLaunchKernelGGL(k_proj,   dim3(1024), dim3(256), 0, stream, attb, wpj, pb, out);
}

// Round 9
// 77.780 us; speedup vs baseline: 1.5397x; 1.0156x over previous
//
#include <hip/hip_runtime.h>
#include <stdint.h>

typedef unsigned short u16;
typedef short s16x8 __attribute__((ext_vector_type(8)));
typedef short s16x4 __attribute__((ext_vector_type(4)));
typedef float f32x4 __attribute__((ext_vector_type(4)));
typedef uint32_t u32x4 __attribute__((ext_vector_type(4)));

#define SCALE 0.17677669529663689f
#define LOG2E 1.4426950408889634f
#define QS (SCALE * LOG2E)
#define EPS 1e-5f

static __device__ __forceinline__ u16 f2b(float f){   // RNE
  uint32_t u = __float_as_uint(f);
  uint32_t r = (u + 0x7FFFu + ((u >> 16) & 1u)) >> 16;
  return (u16)r;
}
static __device__ __forceinline__ uint32_t cvtpk(float lo, float hi){
  uint32_t r;
  asm("v_cvt_pk_bf16_f32 %0, %1, %2" : "=v"(r) : "v"(lo), "v"(hi));
  return r;
}

// ---- K1: depthwise 3x3 Q conv (fp32 x), 8-px strips; Q pre-scaled by SCALE*log2e.
//      Extra blocks (>=2048) repack srw/pw into B-frag order. ----
__global__ __launch_bounds__(256) void k_qconv(const float* __restrict__ x,
                                               const float* __restrict__ w,
                                               const float* __restrict__ srw,
                                               const float* __restrict__ pw,
                                               u16* __restrict__ q,
                                               u16* __restrict__ wsr,
                                               u16* __restrict__ wpj){
  const int blk = blockIdx.x;
  if (blk >= 2048){
    const int t = (blk - 2048)*256 + threadIdx.x;
    if (t < 262144){
      const int co = t >> 10, k = t & 1023;
      const float v = srw[(co<<10) + ((k&255)<<2) + (k>>8)];
      wsr[((((k>>3)<<8) + co)<<3) + (k&7)] = f2b(v);
    } else if (t < 327680){
      const int u2 = t - 262144;
      const int co = u2 >> 8, k = u2 & 255;
      wpj[((((k>>3)<<8) + co)<<3) + (k&7)] = f2b(pw[(co<<8) + k]);
    }
    return;
  }
  const int c = threadIdx.x;
  const int b = blk >> 9;
  const int y = (blk >> 3) & 63;
  const int x0 = (blk & 7) << 3;
  float wv[9];
#pragma unroll
  for (int t = 0; t < 9; ++t) wv[t] = w[c*9 + t];
  float xin[3][10];
#pragma unroll
  for (int r = 0; r < 3; ++r){
    const int yy = y + r - 1;
    const bool yok = (unsigned)yy < 64u;
#pragma unroll
    for (int j = 0; j < 10; ++j){
      const int xx = x0 + j - 1;
      const bool ok = yok && ((unsigned)xx < 64u);
      xin[r][j] = ok ? x[(((b<<12) + (yy<<6) + xx) << 8) + c] : 0.f;
    }
  }
#pragma unroll
  for (int j = 0; j < 8; ++j){
    float acc = 0.f;
#pragma unroll
    for (int r = 0; r < 3; ++r)
#pragma unroll
      for (int t = 0; t < 3; ++t)
        acc += xin[r][j+t] * wv[r*3 + t];
    q[(((b<<12) + (y<<6) + x0 + j) << 8) + c] = f2b(acc * QS);
  }
}

// ---- K2: SR conv as MFMA GEMM (M=4096,N=256,K=1024) + bias + fused LayerNorm ----
// A-frags built directly from fp32 x via v_cvt_pk_bf16_f32 (no xbf dependency)
__global__ __launch_bounds__(256) void k_srgemm(const float* __restrict__ x,
                                                const u16* __restrict__ wsr,
                                                const float* __restrict__ srb,
                                                const float* __restrict__ lng,
                                                const float* __restrict__ lnb,
                                                float* __restrict__ lnxr){
  __shared__ float red_s[16][4], red_q[16][4];
  __shared__ float mu_s[16], rs_s[16];
  const int tid = threadIdx.x;
  const int l = tid & 63, w = tid >> 6;
  const int r15 = l & 15, g = l >> 4;
  const int m0 = blockIdx.x << 4;
  const int ma = m0 + r15;
  const int bb_ = ma >> 10, nk = ma & 1023;
  const int hs = nk >> 5, wsx = nk & 31;
  int pixbase[4];
#pragma unroll
  for (int p = 0; p < 4; ++p){
    const int y = 2*hs + (p>>1), xx = 2*wsx + (p&1);
    pixbase[p] = (((bb_<<12) + (y<<6) + xx) << 8);
  }
  f32x4 acc[4];
#pragma unroll
  for (int i = 0; i < 4; ++i) acc[i] = (f32x4){0.f,0.f,0.f,0.f};
  for (int ks = 0; ks < 32; ++ks){
    const float* ap = x + pixbase[ks>>3] + ((ks&7)<<5) + (g<<3);
    const float4 a0 = *reinterpret_cast<const float4*>(ap);
    const float4 a1 = *reinterpret_cast<const float4*>(ap + 4);
    const u32x4 apk = {cvtpk(a0.x,a0.y), cvtpk(a0.z,a0.w),
                       cvtpk(a1.x,a1.y), cvtpk(a1.z,a1.w)};
    const s16x8 af = __builtin_bit_cast(s16x8, apk);
#pragma unroll
    for (int i = 0; i < 4; ++i){
      const int co = (((w<<2)+i)<<4) + r15;
      const s16x8 bf = *reinterpret_cast<const s16x8*>(
          wsr + (((((ks<<2)+g)<<8) + co)<<3));
      acc[i] = __builtin_amdgcn_mfma_f32_16x16x32_bf16(af, bf, acc[i], 0, 0, 0);
    }
  }
  float gv[4], bv[4];
#pragma unroll
  for (int i = 0; i < 4; ++i){
    const int co = (((w<<2)+i)<<4) + r15;
    const float sb = srb[co];
    gv[i] = lng[co]; bv[i] = lnb[co];
#pragma unroll
    for (int r = 0; r < 4; ++r) acc[i][r] += sb;
  }
  float s_r[4], q_r[4];
#pragma unroll
  for (int r = 0; r < 4; ++r){
    float s = 0.f, qq = 0.f;
#pragma unroll
    for (int i = 0; i < 4; ++i){ const float v = acc[i][r]; s += v; qq += v*v; }
#pragma unroll
    for (int off = 1; off < 16; off <<= 1){
      s  += __shfl_xor(s, off);
      qq += __shfl_xor(qq, off);
    }
    s_r[r] = s; q_r[r] = qq;
  }
  if (r15 == 0){
#pragma unroll
    for (int r = 0; r < 4; ++r){
      red_s[(g<<2)+r][w] = s_r[r];
      red_q[(g<<2)+r][w] = q_r[r];
    }
  }
  __syncthreads();
  if (tid < 16){
    const float s  = red_s[tid][0]+red_s[tid][1]+red_s[tid][2]+red_s[tid][3];
    const float qq = red_q[tid][0]+red_q[tid][1]+red_q[tid][2]+red_q[tid][3];
    const float mu = s * (1.f/256.f);
    mu_s[tid] = mu;
    rs_s[tid] = rsqrtf(qq*(1.f/256.f) - mu*mu + EPS);
  }
  __syncthreads();
  float mur[4], rsr[4];
#pragma unroll
  for (int r = 0; r < 4; ++r){ mur[r] = mu_s[(g<<2)+r]; rsr[r] = rs_s[(g<<2)+r]; }
#pragma unroll
  for (int i = 0; i < 4; ++i){
    const int co = (((w<<2)+i)<<4) + r15;
#pragma unroll
    for (int r = 0; r < 4; ++r)
      lnxr[(m0+(g<<2)+r)*256 + co] = (acc[i][r]-mur[r])*rsr[r]*gv[i] + bv[i];
  }
}

// ---- K3: depthwise 3x3 KV conv, 8-px strips; K [bh,nk,32], V [bh,32,Nk] (block-swizzled) ----
__global__ __launch_bounds__(512) void k_kvconv(const float* __restrict__ lnxr,
                                                const float* __restrict__ w,
                                                u16* __restrict__ kbuf,
                                                u16* __restrict__ vT){
  const int o = threadIdx.x;             // 0..511
  const int blk = blockIdx.x;            // b*128 + y*4 + xs
  const int b = blk >> 7;
  const int y = (blk >> 2) & 31;
  const int x0 = (blk & 3) << 3;
  const int g = o >> 1;
  float wv[9];
#pragma unroll
  for (int t = 0; t < 9; ++t) wv[t] = w[o*9 + t];
  float xin[3][10];
#pragma unroll
  for (int r = 0; r < 3; ++r){
    const int yy = y + r - 1;
    const bool yok = (unsigned)yy < 32u;
#pragma unroll
    for (int j = 0; j < 10; ++j){
      const int xx = x0 + j - 1;
      const bool ok = yok && ((unsigned)xx < 32u);
      xin[r][j] = ok ? lnxr[(((b<<10) + (yy<<5) + xx) << 8) + g] : 0.f;
    }
  }
  float acc[8];
#pragma unroll
  for (int j = 0; j < 8; ++j){
    float a = 0.f;
#pragma unroll
    for (int r = 0; r < 3; ++r)
#pragma unroll
      for (int t = 0; t < 3; ++t)
        a += xin[r][j+t] * wv[r*3 + t];
    acc[j] = a;
  }
  const int t = o & 255;
  const int h = t >> 5, dd = t & 31;
  if (o < 256){
    const int nkbase = (((b<<3) + h) << 10) + (y<<5) + x0;
#pragma unroll
    for (int j = 0; j < 8; ++j)
      kbuf[((nkbase + j) << 5) + dd] = f2b(acc[j]);
  } else {
    s16x8 pack;
#pragma unroll
    for (int j = 0; j < 8; ++j) pack[j] = (short)f2b(acc[j]);
    const int col0 = (y<<5) + x0;
    const int colS = (((col0>>3) ^ (dd&7)) << 3);   // 16B-block XOR swizzle
    *reinterpret_cast<s16x8*>(
        vT + (((((b<<3) + h) << 5) + dd) << 10) + colS) = pack;
  }
}

// ---- K4: MFMA flash attention; whole-head K/V in LDS; 1024-thr blocks (16 waves x 32 q) ----
__global__ __launch_bounds__(1024, 4) void k_attn(const u16* __restrict__ q,
                                                  const u16* __restrict__ kbuf,
                                                  const u16* __restrict__ vT,
                                                  u16* __restrict__ attb){
  __shared__ __align__(16) u16 KL[32768];   // [nk][32]
  __shared__ __align__(16) u16 VL[32768];   // [d][1024], 16B blocks swizzled by d&7
  const int tid = threadIdx.x;
  const int l = tid & 63, w = tid >> 6;     // 16 waves
  const int i = blockIdx.x;
  const int xcd = i & 7, slot = i >> 3;
  const int bh = (xcd<<2) + (slot>>3);
  const int chunk = slot & 7;
  const int b = bh >> 3, h = bh & 7;
  const int r15 = l & 15, g = l >> 4;
  const int n0 = (chunk<<9) + (w<<5);       // this wave's 32 queries

  {
    const uint4* kg = (const uint4*)(kbuf + (bh<<15));
    const uint4* vg = (const uint4*)(vT   + (bh<<15));
    uint4* kl = (uint4*)KL;
    uint4* vl = (uint4*)VL;
#pragma unroll
    for (int r = 0; r < 4; ++r){
      kl[(r<<10) + tid] = kg[(r<<10) + tid];
      vl[(r<<10) + tid] = vg[(r<<10) + tid];
    }
  }
  __syncthreads();

  s16x8 qf[2];
#pragma unroll
  for (int qi = 0; qi < 2; ++qi)
    qf[qi] = *reinterpret_cast<const s16x8*>(
        q + (((b<<12) + n0 + (qi<<4) + r15) << 8) + (h<<5) + (g<<3));

  f32x4 acc[2][2];
#pragma unroll
  for (int qi = 0; qi < 2; ++qi){
    acc[qi][0] = (f32x4){0.f,0.f,0.f,0.f};
    acc[qi][1] = (f32x4){0.f,0.f,0.f,0.f};
  }
  const f32x4 zero = {0.f,0.f,0.f,0.f};
  float lsum[2] = {0.f,0.f};
  const int vswz = (r15 & 7);

  for (int kv0 = 0; kv0 < 1024; kv0 += 64){
    s16x8 kf[4];
#pragma unroll
    for (int st = 0; st < 4; ++st)
      kf[st] = *reinterpret_cast<const s16x8*>(
          KL + ((kv0 + (st<<4) + r15) << 5) + (g<<3));
    s16x8 vf[2][2];
#pragma unroll
    for (int pr = 0; pr < 2; ++pr)
#pragma unroll
      for (int h2 = 0; h2 < 2; ++h2){
        const int cl  = kv0 + (pr<<5) + (g<<2);
        const int cl2 = cl + 16;
        const int rb  = ((h2<<4) + r15) << 10;
        const s16x4 v0 = *reinterpret_cast<const s16x4*>(
            VL + rb + (((cl >>3) ^ vswz) << 3) + (cl &7));
        const s16x4 v1 = *reinterpret_cast<const s16x4*>(
            VL + rb + (((cl2>>3) ^ vswz) << 3) + (cl2&7));
        s16x8 vv;
        vv[0]=v0[0]; vv[1]=v0[1]; vv[2]=v0[2]; vv[3]=v0[3];
        vv[4]=v1[0]; vv[5]=v1[1]; vv[6]=v1[2]; vv[7]=v1[3];
        vf[pr][h2] = vv;
      }
#pragma unroll
    for (int qi = 0; qi < 2; ++qi){
      f32x4 s[4];
      __builtin_amdgcn_s_setprio(1);
#pragma unroll
      for (int st = 0; st < 4; ++st)
        s[st] = __builtin_amdgcn_mfma_f32_16x16x32_bf16(kf[st], qf[qi], zero, 0, 0, 0);
      __builtin_amdgcn_s_setprio(0);
      float p[4][4];
      float ps = 0.f;
#pragma unroll
      for (int st = 0; st < 4; ++st)
#pragma unroll
        for (int r = 0; r < 4; ++r){
          const float e = __builtin_amdgcn_exp2f(s[st][r]);
          p[st][r] = e;
          ps += e;
        }
      ps += __shfl_xor(ps, 16);
      ps += __shfl_xor(ps, 32);
      lsum[qi] += ps;
      const u32x4 pk0 = {cvtpk(p[0][0],p[0][1]), cvtpk(p[0][2],p[0][3]),
                         cvtpk(p[1][0],p[1][1]), cvtpk(p[1][2],p[1][3])};
      const u32x4 pk1 = {cvtpk(p[2][0],p[2][1]), cvtpk(p[2][2],p[2][3]),
                         cvtpk(p[3][0],p[3][1]), cvtpk(p[3][2],p[3][3])};
      const s16x8 pf0 = __builtin_bit_cast(s16x8, pk0);
      const s16x8 pf1 = __builtin_bit_cast(s16x8, pk1);
      __builtin_amdgcn_s_setprio(1);
#pragma unroll
      for (int h2 = 0; h2 < 2; ++h2){
        acc[qi][h2] = __builtin_amdgcn_mfma_f32_16x16x32_bf16(pf0, vf[0][h2], acc[qi][h2], 0, 0, 0);
        acc[qi][h2] = __builtin_amdgcn_mfma_f32_16x16x32_bf16(pf1, vf[1][h2], acc[qi][h2], 0, 0, 0);
      }
      __builtin_amdgcn_s_setprio(0);
    }
  }
#pragma unroll
  for (int qi = 0; qi < 2; ++qi){
    const float linv = 1.f / lsum[qi];
#pragma unroll
    for (int r = 0; r < 4; ++r){
      const float fl = __shfl(linv, (g<<2) + r);
      const int n = n0 + (qi<<4) + (g<<2) + r;
      u16* orow = attb + (((b<<12) + n) << 8) + (h<<5) + r15;
      orow[0]  = f2b(acc[qi][0][r] * fl);
      orow[16] = f2b(acc[qi][1][r] * fl);
    }
  }
}

// ---- K5: projection as MFMA GEMM (M=16384,N=256,K=256) + bias ----
__global__ __launch_bounds__(256) void k_proj(const u16* __restrict__ attb,
                                              const u16* __restrict__ wpj,
                                              const float* __restrict__ pb,
                                              float* __restrict__ out){
  const int tid = threadIdx.x;
  const int l = tid & 63, w = tid >> 6;
  const int r15 = l & 15, g = l >> 4;
  const int m0 = blockIdx.x << 4;
  f32x4 acc[4];
#pragma unroll
  for (int i = 0; i < 4; ++i) acc[i] = (f32x4){0.f,0.f,0.f,0.f};
  const u16* arow = attb + (m0 + r15)*256 + (g<<3);
#pragma unroll
  for (int ks = 0; ks < 8; ++ks){
    const s16x8 af = *reinterpret_cast<const s16x8*>(arow + (ks<<5));
#pragma unroll
    for (int i = 0; i < 4; ++i){
      const int co = (((w<<2)+i)<<4) + r15;
      const s16x8 bf = *reinterpret_cast<const s16x8*>(
          wpj + (((((ks<<2)+g)<<8) + co)<<3));
      acc[i] = __builtin_amdgcn_mfma_f32_16x16x32_bf16(af, bf, acc[i], 0, 0, 0);
    }
  }
#pragma unroll
  for (int i = 0; i < 4; ++i){
    const int co = (((w<<2)+i)<<4) + r15;
    const float pbv = pb[co];
#pragma unroll
    for (int r = 0; r < 4; ++r)
      out[(m0+(g<<2)+r)*256 + co] = acc[i][r] + pbv;
  }
}

extern "C" void kernel_launch(void* const* d_in, const int* in_sizes, int n_in,
                              void* d_out, int out_size, void* d_ws, size_t ws_size,
                              hipStream_t stream){
  const float* x   = (const float*)d_in[0];
  const float* qw  = (const float*)d_in[1];
  const float* kvw = (const float*)d_in[2];
  const float* srw = (const float*)d_in[3];
  const float* srb = (const float*)d_in[4];
  const float* lng = (const float*)d_in[5];
  const float* lnb = (const float*)d_in[6];
  const float* pw  = (const float*)d_in[7];
  const float* pb  = (const float*)d_in[8];
  float* out = (float*)d_out;

  char* ws = (char*)d_ws;
  u16*   qbuf = (u16*)(ws);                   // 8 MiB  [B,N,C] bf16 (pre-scaled)
  u16*   attb = (u16*)(ws + 8388608);         // 8 MiB  [B,N,C] bf16 attention out
  float* lnxr = (float*)(ws + 16777216);      // 4 MiB  [B,Nk,C] f32
  u16*   kbuf = (u16*)(ws + 20971520);        // 2 MiB  [bh,Nk,d] bf16
  u16*   vT   = (u16*)(ws + 23068672);        // 2 MiB  [bh,d,Nk] bf16 (swizzled)
  u16*   wsr  = (u16*)(ws + 25165824);        // 512 KiB repacked SR weights
  u16*   wpj  = (u16*)(ws + 25690112);        // 128 KiB repacked proj weights

  hipLaunchKernelGGL(k_qconv,  dim3(3328), dim3(256),  0, stream, x, qw, srw, pw, qbuf, wsr, wpj);
  hipLaunchKernelGGL(k_srgemm, dim3(256),  dim3(256),  0, stream, x, wsr, srb, lng, lnb, lnxr);
  hipLaunchKernelGGL(k_kvconv, dim3(512),  dim3(512),  0, stream, lnxr, kvw, kbuf, vT);
  hipLaunchKernelGGL(k_attn,   dim3(256),  dim3(1024), 0, stream, qbuf, kbuf, vT, attb);
  hipLaunchKernelGGL(k_proj,   dim3(1024), dim3(256),  0, stream, attb, wpj, pb, out);
}

// Round 10
// 77.757 us; speedup vs baseline: 1.5402x; 1.0003x over previous
//
#include <hip/hip_runtime.h>
#include <stdint.h>

typedef unsigned short u16;
typedef short s16x8 __attribute__((ext_vector_type(8)));
typedef short s16x4 __attribute__((ext_vector_type(4)));
typedef float f32x4 __attribute__((ext_vector_type(4)));
typedef uint32_t u32x4 __attribute__((ext_vector_type(4)));

#define SCALE 0.17677669529663689f
#define LOG2E 1.4426950408889634f
#define QS (SCALE * LOG2E)
#define EPS 1e-5f

static __device__ __forceinline__ u16 f2b(float f){   // RNE
  uint32_t u = __float_as_uint(f);
  uint32_t r = (u + 0x7FFFu + ((u >> 16) & 1u)) >> 16;
  return (u16)r;
}
static __device__ __forceinline__ uint32_t cvtpk(float lo, float hi){
  uint32_t r;
  asm("v_cvt_pk_bf16_f32 %0, %1, %2" : "=v"(r) : "v"(lo), "v"(hi));
  return r;
}

// ---- K0: repack srw into B-frag order (must precede k_front's srgemm blocks) ----
__global__ __launch_bounds__(256) void k_prep(const float* __restrict__ srw,
                                              u16* __restrict__ wsr){
  const int t = blockIdx.x*256 + threadIdx.x;   // 1024 blocks -> t < 262144
  const int co = t >> 10, k = t & 1023;
  const float v = srw[(co<<10) + ((k&255)<<2) + (k>>8)];
  wsr[((((k>>3)<<8) + co)<<3) + (k&7)] = f2b(v);
}

// ---- K1 (merged front): blk<256 = SR-conv GEMM + LayerNorm; blk in [256,2304) =
//      depthwise 3x3 Q conv; blk >= 2304 = proj-weight repack (consumed 3 launches later) ----
__global__ __launch_bounds__(256) void k_front(const float* __restrict__ x,
                                               const float* __restrict__ qw,
                                               const float* __restrict__ pw,
                                               const u16* __restrict__ wsr,
                                               const float* __restrict__ srb,
                                               const float* __restrict__ lng,
                                               const float* __restrict__ lnb,
                                               u16* __restrict__ q,
                                               u16* __restrict__ wpj,
                                               float* __restrict__ lnxr){
  const int blk = blockIdx.x;
  const int tid = threadIdx.x;

  if (blk >= 2304){                      // ---- proj weight repack ----
    const int t = (blk - 2304)*256 + tid;        // t < 65536
    const int co = t >> 8, k = t & 255;
    wpj[((((k>>3)<<8) + co)<<3) + (k&7)] = f2b(pw[(co<<8) + k]);
    return;
  }

  if (blk >= 256){                       // ---- depthwise 3x3 Q conv ----
    const int qb = blk - 256;            // b*512 + y*8 + xs
    const int c = tid;
    const int b = qb >> 9;
    const int y = (qb >> 3) & 63;
    const int x0 = (qb & 7) << 3;
    float wv[9];
#pragma unroll
    for (int t2 = 0; t2 < 9; ++t2) wv[t2] = qw[c*9 + t2];
    float xin[3][10];
#pragma unroll
    for (int r = 0; r < 3; ++r){
      const int yy = y + r - 1;
      const bool yok = (unsigned)yy < 64u;
#pragma unroll
      for (int j = 0; j < 10; ++j){
        const int xx = x0 + j - 1;
        const bool ok = yok && ((unsigned)xx < 64u);
        xin[r][j] = ok ? x[(((b<<12) + (yy<<6) + xx) << 8) + c] : 0.f;
      }
    }
#pragma unroll
    for (int j = 0; j < 8; ++j){
      float acc = 0.f;
#pragma unroll
      for (int r = 0; r < 3; ++r)
#pragma unroll
        for (int t2 = 0; t2 < 3; ++t2)
          acc += xin[r][j+t2] * wv[r*3 + t2];
      q[(((b<<12) + (y<<6) + x0 + j) << 8) + c] = f2b(acc * QS);
    }
    return;
  }

  // ---- SR conv as MFMA GEMM (M=4096,N=256,K=1024) + bias + fused LayerNorm ----
  __shared__ float red_s[16][4], red_q[16][4];
  __shared__ float mu_s[16], rs_s[16];
  const int l = tid & 63, w = tid >> 6;
  const int r15 = l & 15, g = l >> 4;
  const int m0 = blk << 4;
  const int ma = m0 + r15;
  const int bb_ = ma >> 10, nk = ma & 1023;
  const int hs = nk >> 5, wsx = nk & 31;
  int pixbase[4];
#pragma unroll
  for (int p = 0; p < 4; ++p){
    const int y = 2*hs + (p>>1), xx = 2*wsx + (p&1);
    pixbase[p] = (((bb_<<12) + (y<<6) + xx) << 8);
  }
  f32x4 acc[4];
#pragma unroll
  for (int i = 0; i < 4; ++i) acc[i] = (f32x4){0.f,0.f,0.f,0.f};
  for (int ks = 0; ks < 32; ++ks){
    const float* ap = x + pixbase[ks>>3] + ((ks&7)<<5) + (g<<3);
    const float4 a0 = *reinterpret_cast<const float4*>(ap);
    const float4 a1 = *reinterpret_cast<const float4*>(ap + 4);
    const u32x4 apk = {cvtpk(a0.x,a0.y), cvtpk(a0.z,a0.w),
                       cvtpk(a1.x,a1.y), cvtpk(a1.z,a1.w)};
    const s16x8 af = __builtin_bit_cast(s16x8, apk);
#pragma unroll
    for (int i = 0; i < 4; ++i){
      const int co = (((w<<2)+i)<<4) + r15;
      const s16x8 bf = *reinterpret_cast<const s16x8*>(
          wsr + (((((ks<<2)+g)<<8) + co)<<3));
      acc[i] = __builtin_amdgcn_mfma_f32_16x16x32_bf16(af, bf, acc[i], 0, 0, 0);
    }
  }
  float gv[4], bv[4];
#pragma unroll
  for (int i = 0; i < 4; ++i){
    const int co = (((w<<2)+i)<<4) + r15;
    const float sb = srb[co];
    gv[i] = lng[co]; bv[i] = lnb[co];
#pragma unroll
    for (int r = 0; r < 4; ++r) acc[i][r] += sb;
  }
  float s_r[4], q_r[4];
#pragma unroll
  for (int r = 0; r < 4; ++r){
    float s = 0.f, qq = 0.f;
#pragma unroll
    for (int i = 0; i < 4; ++i){ const float v = acc[i][r]; s += v; qq += v*v; }
#pragma unroll
    for (int off = 1; off < 16; off <<= 1){
      s  += __shfl_xor(s, off);
      qq += __shfl_xor(qq, off);
    }
    s_r[r] = s; q_r[r] = qq;
  }
  if (r15 == 0){
#pragma unroll
    for (int r = 0; r < 4; ++r){
      red_s[(g<<2)+r][w] = s_r[r];
      red_q[(g<<2)+r][w] = q_r[r];
    }
  }
  __syncthreads();
  if (tid < 16){
    const float s  = red_s[tid][0]+red_s[tid][1]+red_s[tid][2]+red_s[tid][3];
    const float qq = red_q[tid][0]+red_q[tid][1]+red_q[tid][2]+red_q[tid][3];
    const float mu = s * (1.f/256.f);
    mu_s[tid] = mu;
    rs_s[tid] = rsqrtf(qq*(1.f/256.f) - mu*mu + EPS);
  }
  __syncthreads();
  float mur[4], rsr[4];
#pragma unroll
  for (int r = 0; r < 4; ++r){ mur[r] = mu_s[(g<<2)+r]; rsr[r] = rs_s[(g<<2)+r]; }
#pragma unroll
  for (int i = 0; i < 4; ++i){
    const int co = (((w<<2)+i)<<4) + r15;
#pragma unroll
    for (int r = 0; r < 4; ++r)
      lnxr[(m0+(g<<2)+r)*256 + co] = (acc[i][r]-mur[r])*rsr[r]*gv[i] + bv[i];
  }
}

// ---- K3: depthwise 3x3 KV conv, 8-px strips; K [bh,nk,32], V [bh,32,Nk] (block-swizzled) ----
__global__ __launch_bounds__(512) void k_kvconv(const float* __restrict__ lnxr,
                                                const float* __restrict__ w,
                                                u16* __restrict__ kbuf,
                                                u16* __restrict__ vT){
  const int o = threadIdx.x;             // 0..511
  const int blk = blockIdx.x;            // b*128 + y*4 + xs
  const int b = blk >> 7;
  const int y = (blk >> 2) & 31;
  const int x0 = (blk & 3) << 3;
  const int g = o >> 1;
  float wv[9];
#pragma unroll
  for (int t = 0; t < 9; ++t) wv[t] = w[o*9 + t];
  float xin[3][10];
#pragma unroll
  for (int r = 0; r < 3; ++r){
    const int yy = y + r - 1;
    const bool yok = (unsigned)yy < 32u;
#pragma unroll
    for (int j = 0; j < 10; ++j){
      const int xx = x0 + j - 1;
      const bool ok = yok && ((unsigned)xx < 32u);
      xin[r][j] = ok ? lnxr[(((b<<10) + (yy<<5) + xx) << 8) + g] : 0.f;
    }
  }
  float acc[8];
#pragma unroll
  for (int j = 0; j < 8; ++j){
    float a = 0.f;
#pragma unroll
    for (int r = 0; r < 3; ++r)
#pragma unroll
      for (int t = 0; t < 3; ++t)
        a += xin[r][j+t] * wv[r*3 + t];
    acc[j] = a;
  }
  const int t = o & 255;
  const int h = t >> 5, dd = t & 31;
  if (o < 256){
    const int nkbase = (((b<<3) + h) << 10) + (y<<5) + x0;
#pragma unroll
    for (int j = 0; j < 8; ++j)
      kbuf[((nkbase + j) << 5) + dd] = f2b(acc[j]);
  } else {
    s16x8 pack;
#pragma unroll
    for (int j = 0; j < 8; ++j) pack[j] = (short)f2b(acc[j]);
    const int col0 = (y<<5) + x0;
    const int colS = (((col0>>3) ^ (dd&7)) << 3);   // 16B-block XOR swizzle
    *reinterpret_cast<s16x8*>(
        vT + (((((b<<3) + h) << 5) + dd) << 10) + colS) = pack;
  }
}

// ---- K4: MFMA flash attention; whole-head K/V in LDS; 1024-thr blocks (16 waves x 32 q) ----
__global__ __launch_bounds__(1024, 4) void k_attn(const u16* __restrict__ q,
                                                  const u16* __restrict__ kbuf,
                                                  const u16* __restrict__ vT,
                                                  u16* __restrict__ attb){
  __shared__ __align__(16) u16 KL[32768];   // [nk][32]
  __shared__ __align__(16) u16 VL[32768];   // [d][1024], 16B blocks swizzled by d&7
  const int tid = threadIdx.x;
  const int l = tid & 63, w = tid >> 6;     // 16 waves
  const int i = blockIdx.x;
  const int xcd = i & 7, slot = i >> 3;
  const int bh = (xcd<<2) + (slot>>3);
  const int chunk = slot & 7;
  const int b = bh >> 3, h = bh & 7;
  const int r15 = l & 15, g = l >> 4;
  const int n0 = (chunk<<9) + (w<<5);       // this wave's 32 queries

  {
    const uint4* kg = (const uint4*)(kbuf + (bh<<15));
    const uint4* vg = (const uint4*)(vT   + (bh<<15));
    uint4* kl = (uint4*)KL;
    uint4* vl = (uint4*)VL;
#pragma unroll
    for (int r = 0; r < 4; ++r){
      kl[(r<<10) + tid] = kg[(r<<10) + tid];
      vl[(r<<10) + tid] = vg[(r<<10) + tid];
    }
  }
  __syncthreads();

  s16x8 qf[2];
#pragma unroll
  for (int qi = 0; qi < 2; ++qi)
    qf[qi] = *reinterpret_cast<const s16x8*>(
        q + (((b<<12) + n0 + (qi<<4) + r15) << 8) + (h<<5) + (g<<3));

  f32x4 acc[2][2];
#pragma unroll
  for (int qi = 0; qi < 2; ++qi){
    acc[qi][0] = (f32x4){0.f,0.f,0.f,0.f};
    acc[qi][1] = (f32x4){0.f,0.f,0.f,0.f};
  }
  const f32x4 zero = {0.f,0.f,0.f,0.f};
  float lsum[2] = {0.f,0.f};
  const int vswz = (r15 & 7);

  for (int kv0 = 0; kv0 < 1024; kv0 += 64){
    s16x8 kf[4];
#pragma unroll
    for (int st = 0; st < 4; ++st)
      kf[st] = *reinterpret_cast<const s16x8*>(
          KL + ((kv0 + (st<<4) + r15) << 5) + (g<<3));
    s16x8 vf[2][2];
#pragma unroll
    for (int pr = 0; pr < 2; ++pr)
#pragma unroll
      for (int h2 = 0; h2 < 2; ++h2){
        const int cl  = kv0 + (pr<<5) + (g<<2);
        const int cl2 = cl + 16;
        const int rb  = ((h2<<4) + r15) << 10;
        const s16x4 v0 = *reinterpret_cast<const s16x4*>(
            VL + rb + (((cl >>3) ^ vswz) << 3) + (cl &7));
        const s16x4 v1 = *reinterpret_cast<const s16x4*>(
            VL + rb + (((cl2>>3) ^ vswz) << 3) + (cl2&7));
        s16x8 vv;
        vv[0]=v0[0]; vv[1]=v0[1]; vv[2]=v0[2]; vv[3]=v0[3];
        vv[4]=v1[0]; vv[5]=v1[1]; vv[6]=v1[2]; vv[7]=v1[3];
        vf[pr][h2] = vv;
      }
#pragma unroll
    for (int qi = 0; qi < 2; ++qi){
      f32x4 s[4];
      __builtin_amdgcn_s_setprio(1);
#pragma unroll
      for (int st = 0; st < 4; ++st)
        s[st] = __builtin_amdgcn_mfma_f32_16x16x32_bf16(kf[st], qf[qi], zero, 0, 0, 0);
      __builtin_amdgcn_s_setprio(0);
      float p[4][4];
      float ps = 0.f;
#pragma unroll
      for (int st = 0; st < 4; ++st)
#pragma unroll
        for (int r = 0; r < 4; ++r){
          const float e = __builtin_amdgcn_exp2f(s[st][r]);
          p[st][r] = e;
          ps += e;
        }
      ps += __shfl_xor(ps, 16);
      ps += __shfl_xor(ps, 32);
      lsum[qi] += ps;
      const u32x4 pk0 = {cvtpk(p[0][0],p[0][1]), cvtpk(p[0][2],p[0][3]),
                         cvtpk(p[1][0],p[1][1]), cvtpk(p[1][2],p[1][3])};
      const u32x4 pk1 = {cvtpk(p[2][0],p[2][1]), cvtpk(p[2][2],p[2][3]),
                         cvtpk(p[3][0],p[3][1]), cvtpk(p[3][2],p[3][3])};
      const s16x8 pf0 = __builtin_bit_cast(s16x8, pk0);
      const s16x8 pf1 = __builtin_bit_cast(s16x8, pk1);
      __builtin_amdgcn_s_setprio(1);
#pragma unroll
      for (int h2 = 0; h2 < 2; ++h2){
        acc[qi][h2] = __builtin_amdgcn_mfma_f32_16x16x32_bf16(pf0, vf[0][h2], acc[qi][h2], 0, 0, 0);
        acc[qi][h2] = __builtin_amdgcn_mfma_f32_16x16x32_bf16(pf1, vf[1][h2], acc[qi][h2], 0, 0, 0);
      }
      __builtin_amdgcn_s_setprio(0);
    }
  }
#pragma unroll
  for (int qi = 0; qi < 2; ++qi){
    const float linv = 1.f / lsum[qi];
#pragma unroll
    for (int r = 0; r < 4; ++r){
      const float fl = __shfl(linv, (g<<2) + r);
      const int n = n0 + (qi<<4) + (g<<2) + r;
      u16* orow = attb + (((b<<12) + n) << 8) + (h<<5) + r15;
      orow[0]  = f2b(acc[qi][0][r] * fl);
      orow[16] = f2b(acc[qi][1][r] * fl);
    }
  }
}

// ---- K5: projection as MFMA GEMM (M=16384,N=256,K=256) + bias ----
__global__ __launch_bounds__(256) void k_proj(const u16* __restrict__ attb,
                                              const u16* __restrict__ wpj,
                                              const float* __restrict__ pb,
                                              float* __restrict__ out){
  const int tid = threadIdx.x;
  const int l = tid & 63, w = tid >> 6;
  const int r15 = l & 15, g = l >> 4;
  const int m0 = blockIdx.x << 4;
  f32x4 acc[4];
#pragma unroll
  for (int i = 0; i < 4; ++i) acc[i] = (f32x4){0.f,0.f,0.f,0.f};
  const u16* arow = attb + (m0 + r15)*256 + (g<<3);
#pragma unroll
  for (int ks = 0; ks < 8; ++ks){
    const s16x8 af = *reinterpret_cast<const s16x8*>(arow + (ks<<5));
#pragma unroll
    for (int i = 0; i < 4; ++i){
      const int co = (((w<<2)+i)<<4) + r15;
      const s16x8 bf = *reinterpret_cast<const s16x8*>(
          wpj + (((((ks<<2)+g)<<8) + co)<<3));
      acc[i] = __builtin_amdgcn_mfma_f32_16x16x32_bf16(af, bf, acc[i], 0, 0, 0);
    }
  }
#pragma unroll
  for (int i = 0; i < 4; ++i){
    const int co = (((w<<2)+i)<<4) + r15;
    const float pbv = pb[co];
#pragma unroll
    for (int r = 0; r < 4; ++r)
      out[(m0+(g<<2)+r)*256 + co] = acc[i][r] + pbv;
  }
}

extern "C" void kernel_launch(void* const* d_in, const int* in_sizes, int n_in,
                              void* d_out, int out_size, void* d_ws, size_t ws_size,
                              hipStream_t stream){
  const float* x   = (const float*)d_in[0];
  const float* qw  = (const float*)d_in[1];
  const float* kvw = (const float*)d_in[2];
  const float* srw = (const float*)d_in[3];
  const float* srb = (const float*)d_in[4];
  const float* lng = (const float*)d_in[5];
  const float* lnb = (const float*)d_in[6];
  const float* pw  = (const float*)d_in[7];
  const float* pb  = (const float*)d_in[8];
  float* out = (float*)d_out;

  char* ws = (char*)d_ws;
  u16*   qbuf = (u16*)(ws);                   // 8 MiB  [B,N,C] bf16 (pre-scaled)
  u16*   attb = (u16*)(ws + 8388608);         // 8 MiB  [B,N,C] bf16 attention out
  float* lnxr = (float*)(ws + 16777216);      // 4 MiB  [B,Nk,C] f32
  u16*   kbuf = (u16*)(ws + 20971520);        // 2 MiB  [bh,Nk,d] bf16
  u16*   vT   = (u16*)(ws + 23068672);        // 2 MiB  [bh,d,Nk] bf16 (swizzled)
  u16*   wsr  = (u16*)(ws + 25165824);        // 512 KiB repacked SR weights
  u16*   wpj  = (u16*)(ws + 25690112);        // 128 KiB repacked proj weights

  hipLaunchKernelGGL(k_prep,   dim3(1024), dim3(256),  0, stream, srw, wsr);
  hipLaunchKernelGGL(k_front,  dim3(2560), dim3(256),  0, stream,
                     x, qw, pw, wsr, srb, lng, lnb, qbuf, wpj, lnxr);
  hipLaunchKernelGGL(k_kvconv, dim3(512),  dim3(512),  0, stream, lnxr, kvw, kbuf, vT);
  hipLaunchKernelGGL(k_attn,   dim3(256),  dim3(1024), 0, stream, qbuf, kbuf, vT, attb);
  hipLaunchKernelGGL(k_proj,   dim3(1024), dim3(256),  0, stream, attb, wpj, pb, out);
}

// Round 11
// 77.164 us; speedup vs baseline: 1.5520x; 1.0077x over previous
//
#include <hip/hip_runtime.h>
#include <stdint.h>

typedef unsigned short u16;
typedef short s16x8 __attribute__((ext_vector_type(8)));
typedef short s16x4 __attribute__((ext_vector_type(4)));
typedef float f32x4 __attribute__((ext_vector_type(4)));
typedef uint32_t u32x4 __attribute__((ext_vector_type(4)));

#define SCALE 0.17677669529663689f
#define LOG2E 1.4426950408889634f
#define QS (SCALE * LOG2E)
#define EPS 1e-5f

static __device__ __forceinline__ u16 f2b(float f){   // RNE
  uint32_t u = __float_as_uint(f);
  uint32_t r = (u + 0x7FFFu + ((u >> 16) & 1u)) >> 16;
  return (u16)r;
}
static __device__ __forceinline__ uint32_t cvtpk(float lo, float hi){
  uint32_t r;
  asm("v_cvt_pk_bf16_f32 %0, %1, %2" : "=v"(r) : "v"(lo), "v"(hi));
  return r;
}

// ---- K0: repack srw into B-frag order (must precede k_front's srgemm blocks) ----
__global__ __launch_bounds__(256) void k_prep(const float* __restrict__ srw,
                                              u16* __restrict__ wsr){
  const int t = blockIdx.x*256 + threadIdx.x;   // 1024 blocks -> t < 262144
  const int co = t >> 10, k = t & 1023;
  const float v = srw[(co<<10) + ((k&255)<<2) + (k>>8)];
  wsr[((((k>>3)<<8) + co)<<3) + (k&7)] = f2b(v);
}

// ---- K1 (merged front): blk<256 = SR-conv GEMM + LayerNorm; blk in [256,2304) =
//      depthwise 3x3 Q conv; blk >= 2304 = proj-weight repack ----
__global__ __launch_bounds__(256) void k_front(const float* __restrict__ x,
                                               const float* __restrict__ qw,
                                               const float* __restrict__ pw,
                                               const u16* __restrict__ wsr,
                                               const float* __restrict__ srb,
                                               const float* __restrict__ lng,
                                               const float* __restrict__ lnb,
                                               u16* __restrict__ q,
                                               u16* __restrict__ wpj,
                                               float* __restrict__ lnxr){
  const int blk = blockIdx.x;
  const int tid = threadIdx.x;

  if (blk >= 2304){                      // ---- proj weight repack ----
    const int t = (blk - 2304)*256 + tid;        // t < 65536
    const int co = t >> 8, k = t & 255;
    wpj[((((k>>3)<<8) + co)<<3) + (k&7)] = f2b(pw[(co<<8) + k]);
    return;
  }

  if (blk >= 256){                       // ---- depthwise 3x3 Q conv ----
    const int qb = blk - 256;            // b*512 + y*8 + xs
    const int c = tid;
    const int b = qb >> 9;
    const int y = (qb >> 3) & 63;
    const int x0 = (qb & 7) << 3;
    float wv[9];
#pragma unroll
    for (int t2 = 0; t2 < 9; ++t2) wv[t2] = qw[c*9 + t2];
    float xin[3][10];
#pragma unroll
    for (int r = 0; r < 3; ++r){
      const int yy = y + r - 1;
      const bool yok = (unsigned)yy < 64u;
#pragma unroll
      for (int j = 0; j < 10; ++j){
        const int xx = x0 + j - 1;
        const bool ok = yok && ((unsigned)xx < 64u);
        xin[r][j] = ok ? x[(((b<<12) + (yy<<6) + xx) << 8) + c] : 0.f;
      }
    }
#pragma unroll
    for (int j = 0; j < 8; ++j){
      float acc = 0.f;
#pragma unroll
      for (int r = 0; r < 3; ++r)
#pragma unroll
        for (int t2 = 0; t2 < 3; ++t2)
          acc += xin[r][j+t2] * wv[r*3 + t2];
      q[(((b<<12) + (y<<6) + x0 + j) << 8) + c] = f2b(acc * QS);
    }
    return;
  }

  // ---- SR conv as MFMA GEMM (M=4096,N=256,K=1024) + bias + fused LayerNorm ----
  __shared__ float red_s[16][4], red_q[16][4];
  __shared__ float mu_s[16], rs_s[16];
  const int l = tid & 63, w = tid >> 6;
  const int r15 = l & 15, g = l >> 4;
  const int m0 = blk << 4;
  const int ma = m0 + r15;
  const int bb_ = ma >> 10, nk = ma & 1023;
  const int hs = nk >> 5, wsx = nk & 31;
  int pixbase[4];
#pragma unroll
  for (int p = 0; p < 4; ++p){
    const int y = 2*hs + (p>>1), xx = 2*wsx + (p&1);
    pixbase[p] = (((bb_<<12) + (y<<6) + xx) << 8);
  }
  f32x4 acc[4];
#pragma unroll
  for (int i = 0; i < 4; ++i) acc[i] = (f32x4){0.f,0.f,0.f,0.f};
  for (int ks = 0; ks < 32; ++ks){
    const float* ap = x + pixbase[ks>>3] + ((ks&7)<<5) + (g<<3);
    const float4 a0 = *reinterpret_cast<const float4*>(ap);
    const float4 a1 = *reinterpret_cast<const float4*>(ap + 4);
    const u32x4 apk = {cvtpk(a0.x,a0.y), cvtpk(a0.z,a0.w),
                       cvtpk(a1.x,a1.y), cvtpk(a1.z,a1.w)};
    const s16x8 af = __builtin_bit_cast(s16x8, apk);
#pragma unroll
    for (int i = 0; i < 4; ++i){
      const int co = (((w<<2)+i)<<4) + r15;
      const s16x8 bf = *reinterpret_cast<const s16x8*>(
          wsr + (((((ks<<2)+g)<<8) + co)<<3));
      acc[i] = __builtin_amdgcn_mfma_f32_16x16x32_bf16(af, bf, acc[i], 0, 0, 0);
    }
  }
  float gv[4], bv[4];
#pragma unroll
  for (int i = 0; i < 4; ++i){
    const int co = (((w<<2)+i)<<4) + r15;
    const float sb = srb[co];
    gv[i] = lng[co]; bv[i] = lnb[co];
#pragma unroll
    for (int r = 0; r < 4; ++r) acc[i][r] += sb;
  }
  float s_r[4], q_r[4];
#pragma unroll
  for (int r = 0; r < 4; ++r){
    float s = 0.f, qq = 0.f;
#pragma unroll
    for (int i = 0; i < 4; ++i){ const float v = acc[i][r]; s += v; qq += v*v; }
#pragma unroll
    for (int off = 1; off < 16; off <<= 1){
      s  += __shfl_xor(s, off);
      qq += __shfl_xor(qq, off);
    }
    s_r[r] = s; q_r[r] = qq;
  }
  if (r15 == 0){
#pragma unroll
    for (int r = 0; r < 4; ++r){
      red_s[(g<<2)+r][w] = s_r[r];
      red_q[(g<<2)+r][w] = q_r[r];
    }
  }
  __syncthreads();
  if (tid < 16){
    const float s  = red_s[tid][0]+red_s[tid][1]+red_s[tid][2]+red_s[tid][3];
    const float qq = red_q[tid][0]+red_q[tid][1]+red_q[tid][2]+red_q[tid][3];
    const float mu = s * (1.f/256.f);
    mu_s[tid] = mu;
    rs_s[tid] = rsqrtf(qq*(1.f/256.f) - mu*mu + EPS);
  }
  __syncthreads();
  float mur[4], rsr[4];
#pragma unroll
  for (int r = 0; r < 4; ++r){ mur[r] = mu_s[(g<<2)+r]; rsr[r] = rs_s[(g<<2)+r]; }
#pragma unroll
  for (int i = 0; i < 4; ++i){
    const int co = (((w<<2)+i)<<4) + r15;
#pragma unroll
    for (int r = 0; r < 4; ++r)
      lnxr[(m0+(g<<2)+r)*256 + co] = (acc[i][r]-mur[r])*rsr[r]*gv[i] + bv[i];
  }
}

// ---- K3: depthwise 3x3 KV conv, 8-px strips; K [bh,nk,32], V [bh,32,Nk] (block-swizzled) ----
__global__ __launch_bounds__(512) void k_kvconv(const float* __restrict__ lnxr,
                                                const float* __restrict__ w,
                                                u16* __restrict__ kbuf,
                                                u16* __restrict__ vT){
  const int o = threadIdx.x;             // 0..511
  const int blk = blockIdx.x;            // b*128 + y*4 + xs
  const int b = blk >> 7;
  const int y = (blk >> 2) & 31;
  const int x0 = (blk & 3) << 3;
  const int g = o >> 1;
  float wv[9];
#pragma unroll
  for (int t = 0; t < 9; ++t) wv[t] = w[o*9 + t];
  float xin[3][10];
#pragma unroll
  for (int r = 0; r < 3; ++r){
    const int yy = y + r - 1;
    const bool yok = (unsigned)yy < 32u;
#pragma unroll
    for (int j = 0; j < 10; ++j){
      const int xx = x0 + j - 1;
      const bool ok = yok && ((unsigned)xx < 32u);
      xin[r][j] = ok ? lnxr[(((b<<10) + (yy<<5) + xx) << 8) + g] : 0.f;
    }
  }
  float acc[8];
#pragma unroll
  for (int j = 0; j < 8; ++j){
    float a = 0.f;
#pragma unroll
    for (int r = 0; r < 3; ++r)
#pragma unroll
      for (int t = 0; t < 3; ++t)
        a += xin[r][j+t] * wv[r*3 + t];
    acc[j] = a;
  }
  const int t = o & 255;
  const int h = t >> 5, dd = t & 31;
  if (o < 256){
    const int nkbase = (((b<<3) + h) << 10) + (y<<5) + x0;
#pragma unroll
    for (int j = 0; j < 8; ++j)
      kbuf[((nkbase + j) << 5) + dd] = f2b(acc[j]);
  } else {
    s16x8 pack;
#pragma unroll
    for (int j = 0; j < 8; ++j) pack[j] = (short)f2b(acc[j]);
    const int col0 = (y<<5) + x0;
    const int colS = (((col0>>3) ^ (dd&7)) << 3);   // 16B-block XOR swizzle
    *reinterpret_cast<s16x8*>(
        vT + (((((b<<3) + h) << 5) + dd) << 10) + colS) = pack;
  }
}

// ---- K4: MFMA flash attention; whole-head K/V in LDS; 512-thr blocks (8 waves x 64 q),
//      kv loop unroll 2, deferred lsum reduction, vectorized partial sums ----
__global__ __launch_bounds__(512) void k_attn(const u16* __restrict__ q,
                                              const u16* __restrict__ kbuf,
                                              const u16* __restrict__ vT,
                                              u16* __restrict__ attb){
  __shared__ __align__(16) u16 KL[32768];   // [nk][32]
  __shared__ __align__(16) u16 VL[32768];   // [d][1024], 16B blocks swizzled by d&7
  const int tid = threadIdx.x;
  const int l = tid & 63, w = tid >> 6;     // 8 waves
  const int i = blockIdx.x;
  const int xcd = i & 7, slot = i >> 3;
  const int bh = (xcd<<2) + (slot>>3);
  const int chunk = slot & 7;
  const int b = bh >> 3, h = bh & 7;
  const int r15 = l & 15, g = l >> 4;
  const int n0 = (chunk<<9) + (w<<6);       // this wave's 64 queries

  {
    const uint4* kg = (const uint4*)(kbuf + (bh<<15));
    const uint4* vg = (const uint4*)(vT   + (bh<<15));
    uint4* kl = (uint4*)KL;
    uint4* vl = (uint4*)VL;
#pragma unroll
    for (int r = 0; r < 8; ++r){
      kl[(r<<9) + tid] = kg[(r<<9) + tid];
      vl[(r<<9) + tid] = vg[(r<<9) + tid];
    }
  }
  __syncthreads();

  s16x8 qf[4];
#pragma unroll
  for (int qi = 0; qi < 4; ++qi)
    qf[qi] = *reinterpret_cast<const s16x8*>(
        q + (((b<<12) + n0 + (qi<<4) + r15) << 8) + (h<<5) + (g<<3));

  f32x4 acc[4][2];
#pragma unroll
  for (int qi = 0; qi < 4; ++qi){
    acc[qi][0] = (f32x4){0.f,0.f,0.f,0.f};
    acc[qi][1] = (f32x4){0.f,0.f,0.f,0.f};
  }
  const f32x4 zero = {0.f,0.f,0.f,0.f};
  float lsum[4] = {0.f,0.f,0.f,0.f};
  const int vswz = (r15 & 7);

#pragma unroll 2
  for (int kv0 = 0; kv0 < 1024; kv0 += 64){
    s16x8 kf[4];
#pragma unroll
    for (int st = 0; st < 4; ++st)
      kf[st] = *reinterpret_cast<const s16x8*>(
          KL + ((kv0 + (st<<4) + r15) << 5) + (g<<3));
    s16x8 vf[2][2];
#pragma unroll
    for (int pr = 0; pr < 2; ++pr)
#pragma unroll
      for (int h2 = 0; h2 < 2; ++h2){
        const int cl  = kv0 + (pr<<5) + (g<<2);
        const int cl2 = cl + 16;
        const int rb  = ((h2<<4) + r15) << 10;
        const s16x4 v0 = *reinterpret_cast<const s16x4*>(
            VL + rb + (((cl >>3) ^ vswz) << 3) + (cl &7));
        const s16x4 v1 = *reinterpret_cast<const s16x4*>(
            VL + rb + (((cl2>>3) ^ vswz) << 3) + (cl2&7));
        s16x8 vv;
        vv[0]=v0[0]; vv[1]=v0[1]; vv[2]=v0[2]; vv[3]=v0[3];
        vv[4]=v1[0]; vv[5]=v1[1]; vv[6]=v1[2]; vv[7]=v1[3];
        vf[pr][h2] = vv;
      }
#pragma unroll
    for (int qi = 0; qi < 4; ++qi){
      f32x4 s[4];
      __builtin_amdgcn_s_setprio(1);
#pragma unroll
      for (int st = 0; st < 4; ++st)
        s[st] = __builtin_amdgcn_mfma_f32_16x16x32_bf16(kf[st], qf[qi], zero, 0, 0, 0);
      __builtin_amdgcn_s_setprio(0);
      f32x4 e[4];
#pragma unroll
      for (int st = 0; st < 4; ++st)
#pragma unroll
        for (int r = 0; r < 4; ++r)
          e[st][r] = __builtin_amdgcn_exp2f(s[st][r]);
      const f32x4 sum4 = (e[0] + e[1]) + (e[2] + e[3]);
      lsum[qi] += (sum4[0] + sum4[1]) + (sum4[2] + sum4[3]);   // per-lane partial
      const u32x4 pk0 = {cvtpk(e[0][0],e[0][1]), cvtpk(e[0][2],e[0][3]),
                         cvtpk(e[1][0],e[1][1]), cvtpk(e[1][2],e[1][3])};
      const u32x4 pk1 = {cvtpk(e[2][0],e[2][1]), cvtpk(e[2][2],e[2][3]),
                         cvtpk(e[3][0],e[3][1]), cvtpk(e[3][2],e[3][3])};
      const s16x8 pf0 = __builtin_bit_cast(s16x8, pk0);
      const s16x8 pf1 = __builtin_bit_cast(s16x8, pk1);
      __builtin_amdgcn_s_setprio(1);
#pragma unroll
      for (int h2 = 0; h2 < 2; ++h2){
        acc[qi][h2] = __builtin_amdgcn_mfma_f32_16x16x32_bf16(pf0, vf[0][h2], acc[qi][h2], 0, 0, 0);
        acc[qi][h2] = __builtin_amdgcn_mfma_f32_16x16x32_bf16(pf1, vf[1][h2], acc[qi][h2], 0, 0, 0);
      }
      __builtin_amdgcn_s_setprio(0);
    }
  }
  // deferred cross-lane reduction (over g): exact same sum, moved out of loop
#pragma unroll
  for (int qi = 0; qi < 4; ++qi){
    lsum[qi] += __shfl_xor(lsum[qi], 16);
    lsum[qi] += __shfl_xor(lsum[qi], 32);
  }
#pragma unroll
  for (int qi = 0; qi < 4; ++qi){
    const float linv = 1.f / lsum[qi];
#pragma unroll
    for (int r = 0; r < 4; ++r){
      const float fl = __shfl(linv, (g<<2) + r);
      const int n = n0 + (qi<<4) + (g<<2) + r;
      u16* orow = attb + (((b<<12) + n) << 8) + (h<<5) + r15;
      orow[0]  = f2b(acc[qi][0][r] * fl);
      orow[16] = f2b(acc[qi][1][r] * fl);
    }
  }
}

// ---- K5: projection as MFMA GEMM (M=16384,N=256,K=256) + bias ----
__global__ __launch_bounds__(256) void k_proj(const u16* __restrict__ attb,
                                              const u16* __restrict__ wpj,
                                              const float* __restrict__ pb,
                                              float* __restrict__ out){
  const int tid = threadIdx.x;
  const int l = tid & 63, w = tid >> 6;
  const int r15 = l & 15, g = l >> 4;
  const int m0 = blockIdx.x << 4;
  f32x4 acc[4];
#pragma unroll
  for (int i = 0; i < 4; ++i) acc[i] = (f32x4){0.f,0.f,0.f,0.f};
  const u16* arow = attb + (m0 + r15)*256 + (g<<3);
#pragma unroll
  for (int ks = 0; ks < 8; ++ks){
    const s16x8 af = *reinterpret_cast<const s16x8*>(arow + (ks<<5));
#pragma unroll
    for (int i = 0; i < 4; ++i){
      const int co = (((w<<2)+i)<<4) + r15;
      const s16x8 bf = *reinterpret_cast<const s16x8*>(
          wpj + (((((ks<<2)+g)<<8) + co)<<3));
      acc[i] = __builtin_amdgcn_mfma_f32_16x16x32_bf16(af, bf, acc[i], 0, 0, 0);
    }
  }
#pragma unroll
  for (int i = 0; i < 4; ++i){
    const int co = (((w<<2)+i)<<4) + r15;
    const float pbv = pb[co];
#pragma unroll
    for (int r = 0; r < 4; ++r)
      out[(m0+(g<<2)+r)*256 + co] = acc[i][r] + pbv;
  }
}

extern "C" void kernel_launch(void* const* d_in, const int* in_sizes, int n_in,
                              void* d_out, int out_size, void* d_ws, size_t ws_size,
                              hipStream_t stream){
  const float* x   = (const float*)d_in[0];
  const float* qw  = (const float*)d_in[1];
  const float* kvw = (const float*)d_in[2];
  const float* srw = (const float*)d_in[3];
  const float* srb = (const float*)d_in[4];
  const float* lng = (const float*)d_in[5];
  const float* lnb = (const float*)d_in[6];
  const float* pw  = (const float*)d_in[7];
  const float* pb  = (const float*)d_in[8];
  float* out = (float*)d_out;

  char* ws = (char*)d_ws;
  u16*   qbuf = (u16*)(ws);                   // 8 MiB  [B,N,C] bf16 (pre-scaled)
  u16*   attb = (u16*)(ws + 8388608);         // 8 MiB  [B,N,C] bf16 attention out
  float* lnxr = (float*)(ws + 16777216);      // 4 MiB  [B,Nk,C] f32
  u16*   kbuf = (u16*)(ws + 20971520);        // 2 MiB  [bh,Nk,d] bf16
  u16*   vT   = (u16*)(ws + 23068672);        // 2 MiB  [bh,d,Nk] bf16 (swizzled)
  u16*   wsr  = (u16*)(ws + 25165824);        // 512 KiB repacked SR weights
  u16*   wpj  = (u16*)(ws + 25690112);        // 128 KiB repacked proj weights

  hipLaunchKernelGGL(k_prep,   dim3(1024), dim3(256), 0, stream, srw, wsr);
  hipLaunchKernelGGL(k_front,  dim3(2560), dim3(256), 0, stream,
                     x, qw, pw, wsr, srb, lng, lnb, qbuf, wpj, lnxr);
  hipLaunchKernelGGL(k_kvconv, dim3(512),  dim3(512), 0, stream, lnxr, kvw, kbuf, vT);
  hipLaunchKernelGGL(k_attn,   dim3(256),  dim3(512), 0, stream, qbuf, kbuf, vT, attb);
  hipLaunchKernelGGL(k_proj,   dim3(1024), dim3(256), 0, stream, attb, wpj, pb, out);
}

// Round 12
// 74.553 us; speedup vs baseline: 1.6064x; 1.0350x over previous
//
#include <hip/hip_runtime.h>
#include <stdint.h>

typedef unsigned short u16;
typedef short s16x8 __attribute__((ext_vector_type(8)));
typedef short s16x4 __attribute__((ext_vector_type(4)));
typedef float f32x4 __attribute__((ext_vector_type(4)));
typedef uint32_t u32x4 __attribute__((ext_vector_type(4)));

#define SCALE 0.17677669529663689f
#define LOG2E 1.4426950408889634f
#define QS (SCALE * LOG2E)
#define EPS 1e-5f

static __device__ __forceinline__ u16 f2b(float f){   // RNE
  uint32_t u = __float_as_uint(f);
  uint32_t r = (u + 0x7FFFu + ((u >> 16) & 1u)) >> 16;
  return (u16)r;
}
static __device__ __forceinline__ uint32_t cvtpk(float lo, float hi){
  uint32_t r;
  asm("v_cvt_pk_bf16_f32 %0, %1, %2" : "=v"(r) : "v"(lo), "v"(hi));
  return r;
}

// ---- K0: repack srw into B-frag order (must precede k_front's srgemm blocks) ----
__global__ __launch_bounds__(256) void k_prep(const float* __restrict__ srw,
                                              u16* __restrict__ wsr){
  const int t = blockIdx.x*256 + threadIdx.x;   // 1024 blocks -> t < 262144
  const int co = t >> 10, k = t & 1023;
  const float v = srw[(co<<10) + ((k&255)<<2) + (k>>8)];
  wsr[((((k>>3)<<8) + co)<<3) + (k&7)] = f2b(v);
}

// ---- K1 (merged front): blk<256 = SR-conv GEMM + LayerNorm; blk in [256,2304) =
//      depthwise 3x3 Q conv; blk >= 2304 = proj-weight repack ----
__global__ __launch_bounds__(256) void k_front(const float* __restrict__ x,
                                               const float* __restrict__ qw,
                                               const float* __restrict__ pw,
                                               const u16* __restrict__ wsr,
                                               const float* __restrict__ srb,
                                               const float* __restrict__ lng,
                                               const float* __restrict__ lnb,
                                               u16* __restrict__ q,
                                               u16* __restrict__ wpj,
                                               float* __restrict__ lnxr){
  const int blk = blockIdx.x;
  const int tid = threadIdx.x;

  if (blk >= 2304){                      // ---- proj weight repack ----
    const int t = (blk - 2304)*256 + tid;        // t < 65536
    const int co = t >> 8, k = t & 255;
    wpj[((((k>>3)<<8) + co)<<3) + (k&7)] = f2b(pw[(co<<8) + k]);
    return;
  }

  if (blk >= 256){                       // ---- depthwise 3x3 Q conv ----
    const int qb = blk - 256;            // b*512 + y*8 + xs
    const int c = tid;
    const int b = qb >> 9;
    const int y = (qb >> 3) & 63;
    const int x0 = (qb & 7) << 3;
    float wv[9];
#pragma unroll
    for (int t2 = 0; t2 < 9; ++t2) wv[t2] = qw[c*9 + t2];
    float xin[3][10];
#pragma unroll
    for (int r = 0; r < 3; ++r){
      const int yy = y + r - 1;
      const bool yok = (unsigned)yy < 64u;
#pragma unroll
      for (int j = 0; j < 10; ++j){
        const int xx = x0 + j - 1;
        const bool ok = yok && ((unsigned)xx < 64u);
        xin[r][j] = ok ? x[(((b<<12) + (yy<<6) + xx) << 8) + c] : 0.f;
      }
    }
#pragma unroll
    for (int j = 0; j < 8; ++j){
      float acc = 0.f;
#pragma unroll
      for (int r = 0; r < 3; ++r)
#pragma unroll
        for (int t2 = 0; t2 < 3; ++t2)
          acc += xin[r][j+t2] * wv[r*3 + t2];
      q[(((b<<12) + (y<<6) + x0 + j) << 8) + c] = f2b(acc * QS);
    }
    return;
  }

  // ---- SR conv as MFMA GEMM (M=4096,N=256,K=1024) + bias + fused LayerNorm ----
  __shared__ float red_s[16][4], red_q[16][4];
  __shared__ float mu_s[16], rs_s[16];
  const int l = tid & 63, w = tid >> 6;
  const int r15 = l & 15, g = l >> 4;
  const int m0 = blk << 4;
  const int ma = m0 + r15;
  const int bb_ = ma >> 10, nk = ma & 1023;
  const int hs = nk >> 5, wsx = nk & 31;
  int pixbase[4];
#pragma unroll
  for (int p = 0; p < 4; ++p){
    const int y = 2*hs + (p>>1), xx = 2*wsx + (p&1);
    pixbase[p] = (((bb_<<12) + (y<<6) + xx) << 8);
  }
  f32x4 acc[4];
#pragma unroll
  for (int i = 0; i < 4; ++i) acc[i] = (f32x4){0.f,0.f,0.f,0.f};
  for (int ks = 0; ks < 32; ++ks){
    const float* ap = x + pixbase[ks>>3] + ((ks&7)<<5) + (g<<3);
    const float4 a0 = *reinterpret_cast<const float4*>(ap);
    const float4 a1 = *reinterpret_cast<const float4*>(ap + 4);
    const u32x4 apk = {cvtpk(a0.x,a0.y), cvtpk(a0.z,a0.w),
                       cvtpk(a1.x,a1.y), cvtpk(a1.z,a1.w)};
    const s16x8 af = __builtin_bit_cast(s16x8, apk);
#pragma unroll
    for (int i = 0; i < 4; ++i){
      const int co = (((w<<2)+i)<<4) + r15;
      const s16x8 bf = *reinterpret_cast<const s16x8*>(
          wsr + (((((ks<<2)+g)<<8) + co)<<3));
      acc[i] = __builtin_amdgcn_mfma_f32_16x16x32_bf16(af, bf, acc[i], 0, 0, 0);
    }
  }
  float gv[4], bv[4];
#pragma unroll
  for (int i = 0; i < 4; ++i){
    const int co = (((w<<2)+i)<<4) + r15;
    const float sb = srb[co];
    gv[i] = lng[co]; bv[i] = lnb[co];
#pragma unroll
    for (int r = 0; r < 4; ++r) acc[i][r] += sb;
  }
  float s_r[4], q_r[4];
#pragma unroll
  for (int r = 0; r < 4; ++r){
    float s = 0.f, qq = 0.f;
#pragma unroll
    for (int i = 0; i < 4; ++i){ const float v = acc[i][r]; s += v; qq += v*v; }
#pragma unroll
    for (int off = 1; off < 16; off <<= 1){
      s  += __shfl_xor(s, off);
      qq += __shfl_xor(qq, off);
    }
    s_r[r] = s; q_r[r] = qq;
  }
  if (r15 == 0){
#pragma unroll
    for (int r = 0; r < 4; ++r){
      red_s[(g<<2)+r][w] = s_r[r];
      red_q[(g<<2)+r][w] = q_r[r];
    }
  }
  __syncthreads();
  if (tid < 16){
    const float s  = red_s[tid][0]+red_s[tid][1]+red_s[tid][2]+red_s[tid][3];
    const float qq = red_q[tid][0]+red_q[tid][1]+red_q[tid][2]+red_q[tid][3];
    const float mu = s * (1.f/256.f);
    mu_s[tid] = mu;
    rs_s[tid] = rsqrtf(qq*(1.f/256.f) - mu*mu + EPS);
  }
  __syncthreads();
  float mur[4], rsr[4];
#pragma unroll
  for (int r = 0; r < 4; ++r){ mur[r] = mu_s[(g<<2)+r]; rsr[r] = rs_s[(g<<2)+r]; }
#pragma unroll
  for (int i = 0; i < 4; ++i){
    const int co = (((w<<2)+i)<<4) + r15;
#pragma unroll
    for (int r = 0; r < 4; ++r)
      lnxr[(m0+(g<<2)+r)*256 + co] = (acc[i][r]-mur[r])*rsr[r]*gv[i] + bv[i];
  }
}

// ---- K3: depthwise 3x3 KV conv, 8-px strips; K [bh,nk,32], V [bh,32,Nk] (block-swizzled) ----
__global__ __launch_bounds__(512) void k_kvconv(const float* __restrict__ lnxr,
                                                const float* __restrict__ w,
                                                u16* __restrict__ kbuf,
                                                u16* __restrict__ vT){
  const int o = threadIdx.x;             // 0..511
  const int blk = blockIdx.x;            // b*128 + y*4 + xs
  const int b = blk >> 7;
  const int y = (blk >> 2) & 31;
  const int x0 = (blk & 3) << 3;
  const int g = o >> 1;
  float wv[9];
#pragma unroll
  for (int t = 0; t < 9; ++t) wv[t] = w[o*9 + t];
  float xin[3][10];
#pragma unroll
  for (int r = 0; r < 3; ++r){
    const int yy = y + r - 1;
    const bool yok = (unsigned)yy < 32u;
#pragma unroll
    for (int j = 0; j < 10; ++j){
      const int xx = x0 + j - 1;
      const bool ok = yok && ((unsigned)xx < 32u);
      xin[r][j] = ok ? lnxr[(((b<<10) + (yy<<5) + xx) << 8) + g] : 0.f;
    }
  }
  float acc[8];
#pragma unroll
  for (int j = 0; j < 8; ++j){
    float a = 0.f;
#pragma unroll
    for (int r = 0; r < 3; ++r)
#pragma unroll
      for (int t = 0; t < 3; ++t)
        a += xin[r][j+t] * wv[r*3 + t];
    acc[j] = a;
  }
  const int t = o & 255;
  const int h = t >> 5, dd = t & 31;
  if (o < 256){
    const int nkbase = (((b<<3) + h) << 10) + (y<<5) + x0;
#pragma unroll
    for (int j = 0; j < 8; ++j)
      kbuf[((nkbase + j) << 5) + dd] = f2b(acc[j]);
  } else {
    s16x8 pack;
#pragma unroll
    for (int j = 0; j < 8; ++j) pack[j] = (short)f2b(acc[j]);
    const int col0 = (y<<5) + x0;
    const int colS = (((col0>>3) ^ (dd&7)) << 3);   // 16B-block XOR swizzle
    *reinterpret_cast<s16x8*>(
        vT + (((((b<<3) + h) << 5) + dd) << 10) + colS) = pack;
  }
}

// ---- K4: MFMA flash attention; whole-head K/V in LDS; 512-thr blocks (8 waves x 64 q),
//      no setprio (lockstep single-phase loop -> setprio is T5-null/negative regime) ----
__global__ __launch_bounds__(512) void k_attn(const u16* __restrict__ q,
                                              const u16* __restrict__ kbuf,
                                              const u16* __restrict__ vT,
                                              u16* __restrict__ attb){
  __shared__ __align__(16) u16 KL[32768];   // [nk][32]
  __shared__ __align__(16) u16 VL[32768];   // [d][1024], 16B blocks swizzled by d&7
  const int tid = threadIdx.x;
  const int l = tid & 63, w = tid >> 6;     // 8 waves
  const int i = blockIdx.x;
  const int xcd = i & 7, slot = i >> 3;
  const int bh = (xcd<<2) + (slot>>3);
  const int chunk = slot & 7;
  const int b = bh >> 3, h = bh & 7;
  const int r15 = l & 15, g = l >> 4;
  const int n0 = (chunk<<9) + (w<<6);       // this wave's 64 queries

  {
    const uint4* kg = (const uint4*)(kbuf + (bh<<15));
    const uint4* vg = (const uint4*)(vT   + (bh<<15));
    uint4* kl = (uint4*)KL;
    uint4* vl = (uint4*)VL;
#pragma unroll
    for (int r = 0; r < 8; ++r){
      kl[(r<<9) + tid] = kg[(r<<9) + tid];
      vl[(r<<9) + tid] = vg[(r<<9) + tid];
    }
  }
  __syncthreads();

  s16x8 qf[4];
#pragma unroll
  for (int qi = 0; qi < 4; ++qi)
    qf[qi] = *reinterpret_cast<const s16x8*>(
        q + (((b<<12) + n0 + (qi<<4) + r15) << 8) + (h<<5) + (g<<3));

  f32x4 acc[4][2];
#pragma unroll
  for (int qi = 0; qi < 4; ++qi){
    acc[qi][0] = (f32x4){0.f,0.f,0.f,0.f};
    acc[qi][1] = (f32x4){0.f,0.f,0.f,0.f};
  }
  const f32x4 zero = {0.f,0.f,0.f,0.f};
  float lsum[4] = {0.f,0.f,0.f,0.f};
  const int vswz = (r15 & 7);

#pragma unroll 2
  for (int kv0 = 0; kv0 < 1024; kv0 += 64){
    s16x8 kf[4];
#pragma unroll
    for (int st = 0; st < 4; ++st)
      kf[st] = *reinterpret_cast<const s16x8*>(
          KL + ((kv0 + (st<<4) + r15) << 5) + (g<<3));
    s16x8 vf[2][2];
#pragma unroll
    for (int pr = 0; pr < 2; ++pr)
#pragma unroll
      for (int h2 = 0; h2 < 2; ++h2){
        const int cl  = kv0 + (pr<<5) + (g<<2);
        const int cl2 = cl + 16;
        const int rb  = ((h2<<4) + r15) << 10;
        const s16x4 v0 = *reinterpret_cast<const s16x4*>(
            VL + rb + (((cl >>3) ^ vswz) << 3) + (cl &7));
        const s16x4 v1 = *reinterpret_cast<const s16x4*>(
            VL + rb + (((cl2>>3) ^ vswz) << 3) + (cl2&7));
        s16x8 vv;
        vv[0]=v0[0]; vv[1]=v0[1]; vv[2]=v0[2]; vv[3]=v0[3];
        vv[4]=v1[0]; vv[5]=v1[1]; vv[6]=v1[2]; vv[7]=v1[3];
        vf[pr][h2] = vv;
      }
#pragma unroll
    for (int qi = 0; qi < 4; ++qi){
      f32x4 s[4];
#pragma unroll
      for (int st = 0; st < 4; ++st)
        s[st] = __builtin_amdgcn_mfma_f32_16x16x32_bf16(kf[st], qf[qi], zero, 0, 0, 0);
      f32x4 e[4];
#pragma unroll
      for (int st = 0; st < 4; ++st)
#pragma unroll
        for (int r = 0; r < 4; ++r)
          e[st][r] = __builtin_amdgcn_exp2f(s[st][r]);
      const f32x4 sum4 = (e[0] + e[1]) + (e[2] + e[3]);
      lsum[qi] += (sum4[0] + sum4[1]) + (sum4[2] + sum4[3]);   // per-lane partial
      const u32x4 pk0 = {cvtpk(e[0][0],e[0][1]), cvtpk(e[0][2],e[0][3]),
                         cvtpk(e[1][0],e[1][1]), cvtpk(e[1][2],e[1][3])};
      const u32x4 pk1 = {cvtpk(e[2][0],e[2][1]), cvtpk(e[2][2],e[2][3]),
                         cvtpk(e[3][0],e[3][1]), cvtpk(e[3][2],e[3][3])};
      const s16x8 pf0 = __builtin_bit_cast(s16x8, pk0);
      const s16x8 pf1 = __builtin_bit_cast(s16x8, pk1);
#pragma unroll
      for (int h2 = 0; h2 < 2; ++h2){
        acc[qi][h2] = __builtin_amdgcn_mfma_f32_16x16x32_bf16(pf0, vf[0][h2], acc[qi][h2], 0, 0, 0);
        acc[qi][h2] = __builtin_amdgcn_mfma_f32_16x16x32_bf16(pf1, vf[1][h2], acc[qi][h2], 0, 0, 0);
      }
    }
  }
  // deferred cross-lane reduction (over g): exact same sum, moved out of loop
#pragma unroll
  for (int qi = 0; qi < 4; ++qi){
    lsum[qi] += __shfl_xor(lsum[qi], 16);
    lsum[qi] += __shfl_xor(lsum[qi], 32);
  }
#pragma unroll
  for (int qi = 0; qi < 4; ++qi){
    const float linv = 1.f / lsum[qi];
#pragma unroll
    for (int r = 0; r < 4; ++r){
      const float fl = __shfl(linv, (g<<2) + r);
      const int n = n0 + (qi<<4) + (g<<2) + r;
      u16* orow = attb + (((b<<12) + n) << 8) + (h<<5) + r15;
      orow[0]  = f2b(acc[qi][0][r] * fl);
      orow[16] = f2b(acc[qi][1][r] * fl);
    }
  }
}

// ---- K5: projection as MFMA GEMM (M=16384,N=256,K=256) + bias ----
// 512 blocks x 512 thr: 8 waves = 2 m-chunks x 4 co-groups; waves w and w+4 read
// identical B-frag streams -> second reader hits L1; L2 weight traffic halves.
__global__ __launch_bounds__(512) void k_proj(const u16* __restrict__ attb,
                                              const u16* __restrict__ wpj,
                                              const float* __restrict__ pb,
                                              float* __restrict__ out){
  const int tid = threadIdx.x;
  const int l = tid & 63, w = tid >> 6;      // 8 waves
  const int r15 = l & 15, g = l >> 4;
  const int wco = w & 3, wm = w >> 2;        // co-group, m-chunk
  const int m0 = (blockIdx.x << 5) + (wm << 4);
  f32x4 acc[4];
#pragma unroll
  for (int i = 0; i < 4; ++i) acc[i] = (f32x4){0.f,0.f,0.f,0.f};
  const u16* arow = attb + (m0 + r15)*256 + (g<<3);
#pragma unroll
  for (int ks = 0; ks < 8; ++ks){
    const s16x8 af = *reinterpret_cast<const s16x8*>(arow + (ks<<5));
#pragma unroll
    for (int i = 0; i < 4; ++i){
      const int co = (((wco<<2)+i)<<4) + r15;
      const s16x8 bf = *reinterpret_cast<const s16x8*>(
          wpj + (((((ks<<2)+g)<<8) + co)<<3));
      acc[i] = __builtin_amdgcn_mfma_f32_16x16x32_bf16(af, bf, acc[i], 0, 0, 0);
    }
  }
#pragma unroll
  for (int i = 0; i < 4; ++i){
    const int co = (((wco<<2)+i)<<4) + r15;
    const float pbv = pb[co];
#pragma unroll
    for (int r = 0; r < 4; ++r)
      out[(m0+(g<<2)+r)*256 + co] = acc[i][r] + pbv;
  }
}

extern "C" void kernel_launch(void* const* d_in, const int* in_sizes, int n_in,
                              void* d_out, int out_size, void* d_ws, size_t ws_size,
                              hipStream_t stream){
  const float* x   = (const float*)d_in[0];
  const float* qw  = (const float*)d_in[1];
  const float* kvw = (const float*)d_in[2];
  const float* srw = (const float*)d_in[3];
  const float* srb = (const float*)d_in[4];
  const float* lng = (const float*)d_in[5];
  const float* lnb = (const float*)d_in[6];
  const float* pw  = (const float*)d_in[7];
  const float* pb  = (const float*)d_in[8];
  float* out = (float*)d_out;

  char* ws = (char*)d_ws;
  u16*   qbuf = (u16*)(ws);                   // 8 MiB  [B,N,C] bf16 (pre-scaled)
  u16*   attb = (u16*)(ws + 8388608);         // 8 MiB  [B,N,C] bf16 attention out
  float* lnxr = (float*)(ws + 16777216);      // 4 MiB  [B,Nk,C] f32
  u16*   kbuf = (u16*)(ws + 20971520);        // 2 MiB  [bh,Nk,d] bf16
  u16*   vT   = (u16*)(ws + 23068672);        // 2 MiB  [bh,d,Nk] bf16 (swizzled)
  u16*   wsr  = (u16*)(ws + 25165824);        // 512 KiB repacked SR weights
  u16*   wpj  = (u16*)(ws + 25690112);        // 128 KiB repacked proj weights

  hipLaunchKernelGGL(k_prep,   dim3(1024), dim3(256), 0, stream, srw, wsr);
  hipLaunchKernelGGL(k_front,  dim3(2560), dim3(256), 0, stream,
                     x, qw, pw, wsr, srb, lng, lnb, qbuf, wpj, lnxr);
  hipLaunchKernelGGL(k_kvconv, dim3(512),  dim3(512), 0, stream, lnxr, kvw, kbuf, vT);
  hipLaunchKernelGGL(k_attn,   dim3(256),  dim3(512), 0, stream, qbuf, kbuf, vT, attb);
  hipLaunchKernelGGL(k_proj,   dim3(512),  dim3(512), 0, stream, attb, wpj, pb, out);
}